// Round 1
// baseline (6824.888 us; speedup 1.0000x reference)
//
#include <hip/hip_runtime.h>

#define NSUB 20000
#define NREG 100000
#define NEDGE 600000
#define DIM 128
#define LAY 2
#define NOUT 2

// ---------------------------------------------------------------------------
// GEMM: out[r, c] (+)= (A[r,:] @ W[:,c]) * scale[r] + bias[c]
// A: [N,128] row-major, W: [128,128] row-major (staged in LDS),
// block = 256 threads, tile = 64 rows x 128 cols, thread = 8 rows x 4 cols.
// ---------------------------------------------------------------------------
__global__ __launch_bounds__(256) void mm128(
    const float* __restrict__ A, const float* __restrict__ W,
    const float* __restrict__ bias, const float* __restrict__ scale,
    float* __restrict__ out, int N, int accumulate)
{
    __shared__ float sW[DIM * DIM];   // 64 KB -> 2 blocks/CU
    const int t = threadIdx.x;
#pragma unroll
    for (int i = 0; i < 16; ++i) {
        const int idx = (i * 256 + t) * 4;
        *(float4*)(sW + idx) = *(const float4*)(W + idx);
    }
    __syncthreads();

    const int tx = t & 31;          // col group
    const int ty = t >> 5;          // row slot (0..7)
    const int c0 = tx * 4;
    const int rowBase = blockIdx.x * 64 + ty * 8;

    // clamp row indices so loads are always in-bounds; stores are guarded
    const float* pA[8];
#pragma unroll
    for (int i = 0; i < 8; ++i) {
        int r = rowBase + i;
        int rc = r < N ? r : (N - 1);
        pA[i] = A + (size_t)rc * DIM;
    }

    float acc[8][4];
#pragma unroll
    for (int i = 0; i < 8; ++i)
#pragma unroll
        for (int j = 0; j < 4; ++j) acc[i][j] = 0.0f;

    for (int k = 0; k < DIM; k += 4) {
        const float4 w0 = *(const float4*)(sW + (k + 0) * DIM + c0);
        const float4 w1 = *(const float4*)(sW + (k + 1) * DIM + c0);
        const float4 w2 = *(const float4*)(sW + (k + 2) * DIM + c0);
        const float4 w3 = *(const float4*)(sW + (k + 3) * DIM + c0);
#pragma unroll
        for (int i = 0; i < 8; ++i) {
            const float4 a = *(const float4*)(pA[i] + k);
            acc[i][0] += a.x * w0.x + a.y * w1.x + a.z * w2.x + a.w * w3.x;
            acc[i][1] += a.x * w0.y + a.y * w1.y + a.z * w2.y + a.w * w3.y;
            acc[i][2] += a.x * w0.z + a.y * w1.z + a.z * w2.z + a.w * w3.z;
            acc[i][3] += a.x * w0.w + a.y * w1.w + a.z * w2.w + a.w * w3.w;
        }
    }

    float4 bv = make_float4(0.f, 0.f, 0.f, 0.f);
    if (bias) bv = *(const float4*)(bias + c0);

#pragma unroll
    for (int i = 0; i < 8; ++i) {
        const int r = rowBase + i;
        if (r >= N) continue;
        const float s = scale ? scale[r] : 1.0f;
        float4 o;
        o.x = acc[i][0] * s + bv.x;
        o.y = acc[i][1] * s + bv.y;
        o.z = acc[i][2] * s + bv.z;
        o.w = acc[i][3] * s + bv.w;
        float4* po = (float4*)(out + (size_t)r * DIM + c0);
        if (accumulate) {
            float4 p = *po;
            o.x += p.x; o.y += p.y; o.z += p.z; o.w += p.w;
        }
        *po = o;
    }
}

// ---------------------------------------------------------------------------
// Scatter-add of full feature rows: out[dst[e], :] += feat[src[e], :]
// 32 lanes per edge, float4 per lane, unsafe fp32 atomics.
// ---------------------------------------------------------------------------
__global__ void scatter_add_feat(const float* __restrict__ feat,
                                 const int* __restrict__ src,
                                 const int* __restrict__ dst,
                                 float* __restrict__ out, int E)
{
    const int tid = blockIdx.x * 256 + threadIdx.x;
    const int e = tid >> 5;
    if (e >= E) return;
    const int lane = tid & 31;
    const int s = src[e];
    const int d = dst[e];
    const float4 v = *(const float4*)(feat + (size_t)s * DIM + lane * 4);
    float* o = out + (size_t)d * DIM + lane * 4;
    unsafeAtomicAdd(o + 0, v.x);
    unsafeAtomicAdd(o + 1, v.y);
    unsafeAtomicAdd(o + 2, v.z);
    unsafeAtomicAdd(o + 3, v.w);
}

// GCN edge scatter: out[dst, :] += dis[src]*dis[dst] * xw[src, :]
__global__ void gcn_scatter(const float* __restrict__ xw,
                            const int* __restrict__ src,
                            const int* __restrict__ dst,
                            const float* __restrict__ dis,
                            float* __restrict__ out, int E)
{
    const int tid = blockIdx.x * 256 + threadIdx.x;
    const int e = tid >> 5;
    if (e >= E) return;
    const int lane = tid & 31;
    const int s = src[e];
    const int d = dst[e];
    const float nrm = dis[s] * dis[d];
    const float4 v = *(const float4*)(xw + (size_t)s * DIM + lane * 4);
    float* o = out + (size_t)d * DIM + lane * 4;
    unsafeAtomicAdd(o + 0, nrm * v.x);
    unsafeAtomicAdd(o + 1, nrm * v.y);
    unsafeAtomicAdd(o + 2, nrm * v.z);
    unsafeAtomicAdd(o + 3, nrm * v.w);
}

__global__ void count_dst(const int* __restrict__ dst, float* __restrict__ cnt, int E)
{
    const int e = blockIdx.x * 256 + threadIdx.x;
    if (e < E) unsafeAtomicAdd(&cnt[dst[e]], 1.0f);
}

__global__ void fill1(float* __restrict__ p, int n)
{
    const int i = blockIdx.x * 256 + threadIdx.x;
    if (i < n) p[i] = 1.0f;
}

__global__ void recip_max1(float* __restrict__ p, int n)
{
    const int i = blockIdx.x * 256 + threadIdx.x;
    if (i < n) p[i] = 1.0f / fmaxf(p[i], 1.0f);
}

__global__ void rsqrt_inplace(float* __restrict__ p, int n)
{
    const int i = blockIdx.x * 256 + threadIdx.x;
    if (i < n) p[i] = rsqrtf(p[i]);
}

// xrN[r,:] += dis[r]^2 * xw[r,:] + gcn_b[:]
__global__ void selfloop_bias(float* __restrict__ xrN, const float* __restrict__ xw,
                              const float* __restrict__ dis, const float* __restrict__ gb,
                              int N)
{
    const int i = blockIdx.x * 256 + threadIdx.x;   // over N*32 float4 groups
    if (i >= N * 32) return;
    const int r = i >> 5;
    const int c0 = (i & 31) * 4;
    const float d2 = dis[r] * dis[r];
    const float4 v = *(const float4*)(xw + (size_t)r * DIM + c0);
    const float4 b = *(const float4*)(gb + c0);
    float4 o = *(float4*)(xrN + (size_t)r * DIM + c0);
    o.x += d2 * v.x + b.x;
    o.y += d2 * v.y + b.y;
    o.z += d2 * v.z + b.z;
    o.w += d2 * v.w + b.w;
    *(float4*)(xrN + (size_t)r * DIM + c0) = o;
}

// out[r, 0:2] = X[r,:] @ W[128,2] + b[2]
__global__ void lin_out(const float* __restrict__ X, const float* __restrict__ W,
                        const float* __restrict__ b, float* __restrict__ out, int N)
{
    const int r = blockIdx.x * 256 + threadIdx.x;
    if (r >= N) return;
    float a0 = b[0], a1 = b[1];
    const float* xr = X + (size_t)r * DIM;
#pragma unroll 8
    for (int k = 0; k < DIM; k += 4) {
        const float4 x = *(const float4*)(xr + k);
        a0 += x.x * W[(k + 0) * 2 + 0] + x.y * W[(k + 1) * 2 + 0] +
              x.z * W[(k + 2) * 2 + 0] + x.w * W[(k + 3) * 2 + 0];
        a1 += x.x * W[(k + 0) * 2 + 1] + x.y * W[(k + 1) * 2 + 1] +
              x.z * W[(k + 2) * 2 + 1] + x.w * W[(k + 3) * 2 + 1];
    }
    out[(size_t)r * 2 + 0] = a0;
    out[(size_t)r * 2 + 1] = a1;
}

extern "C" void kernel_launch(void* const* d_in, const int* in_sizes, int n_in,
                              void* d_out, int out_size, void* d_ws, size_t ws_size,
                              hipStream_t stream)
{
    const float* x_subject = (const float*)d_in[0];
    const float* x_region  = (const float*)d_in[1];
    const int*   ei_hr     = (const int*)d_in[2];   // [2,E] row0=subj src, row1=reg dst
    const int*   ei_rev    = (const int*)d_in[3];   // [2,E] row0=reg src, row1=subj dst
    const int*   ei_fc     = (const int*)d_in[4];   // [2,E] region-region
    const float* sr_Wl = (const float*)d_in[5];
    const float* sr_Wr = (const float*)d_in[6];
    const float* sr_b  = (const float*)d_in[7];
    const float* rs_Wl = (const float*)d_in[8];
    const float* rs_Wr = (const float*)d_in[9];
    const float* rs_b  = (const float*)d_in[10];
    const float* gcn_W = (const float*)d_in[11];
    const float* gcn_b = (const float*)d_in[12];
    const float* lsW   = (const float*)d_in[13];
    const float* lsb   = (const float*)d_in[14];
    const float* lrW   = (const float*)d_in[15];
    const float* lrb   = (const float*)d_in[16];

    // workspace layout (floats): ~237 MB total
    float* p = (float*)d_ws;
    float* xsA  = p; p += (size_t)NSUB * DIM;
    float* xsB  = p; p += (size_t)NSUB * DIM;
    float* xrA  = p; p += (size_t)NREG * DIM;
    float* xrB  = p; p += (size_t)NREG * DIM;
    float* aggS = p; p += (size_t)NSUB * DIM;
    float* aggR = p; p += (size_t)NREG * DIM;
    float* xw   = p; p += (size_t)NREG * DIM;
    float* invS = p; p += NSUB;    // becomes 1/max(cnt,1)
    float* invR = p; p += NREG;
    float* dis  = p; p += NREG;    // deg^-1/2 for GCN (with self loop)

    const int EB = (NEDGE + 255) / 256;           // 1 thread / edge
    const int EB32 = (NEDGE * 32 + 255) / 256;    // 32 threads / edge

    // ---- degree / norm precompute (edge structure is constant across layers)
    hipMemsetAsync(invS, 0, NSUB * sizeof(float), stream);
    hipMemsetAsync(invR, 0, NREG * sizeof(float), stream);
    fill1<<<(NREG + 255) / 256, 256, 0, stream>>>(dis, NREG);           // self loop
    count_dst<<<EB, 256, 0, stream>>>(ei_rev + NEDGE, invS, NEDGE);
    count_dst<<<EB, 256, 0, stream>>>(ei_hr + NEDGE, invR, NEDGE);
    count_dst<<<EB, 256, 0, stream>>>(ei_fc + NEDGE, dis, NEDGE);
    recip_max1<<<(NSUB + 255) / 256, 256, 0, stream>>>(invS, NSUB);
    recip_max1<<<(NREG + 255) / 256, 256, 0, stream>>>(invR, NREG);
    rsqrt_inplace<<<(NREG + 255) / 256, 256, 0, stream>>>(dis, NREG);

    const float* cxs = x_subject;
    const float* cxr = x_region;
    const int SB = (NSUB + 63) / 64;
    const int RB = (NREG + 63) / 64;

    for (int l = 0; l < LAY; ++l) {
        float* nxs = (l == 0) ? xsA : xsB;
        float* nxr = (l == 0) ? xrA : xrB;
        const size_t wOff = (size_t)l * DIM * DIM;
        const size_t bOff = (size_t)l * DIM;

        hipMemsetAsync(aggS, 0, (size_t)NSUB * DIM * sizeof(float), stream);
        hipMemsetAsync(aggR, 0, (size_t)NREG * DIM * sizeof(float), stream);

        // segment sums (means deferred to GEMM row-scale)
        scatter_add_feat<<<EB32, 256, 0, stream>>>(cxr, ei_rev, ei_rev + NEDGE, aggS, NEDGE);
        scatter_add_feat<<<EB32, 256, 0, stream>>>(cxs, ei_hr, ei_hr + NEDGE, aggR, NEDGE);

        // new_s = mean_s @ rs_Wl + xs @ rs_Wr + rs_b
        mm128<<<SB, 256, 0, stream>>>(aggS, rs_Wl + wOff, rs_b + bOff, invS, nxs, NSUB, 0);
        mm128<<<SB, 256, 0, stream>>>(cxs, rs_Wr + wOff, nullptr, nullptr, nxs, NSUB, 1);

        // GCN: xw = xr @ gcn_W
        mm128<<<RB, 256, 0, stream>>>(cxr, gcn_W + wOff, nullptr, nullptr, xw, NREG, 0);

        // new_r = mean_r @ sr_Wl + xr @ sr_Wr + sr_b  (+ gcn terms below)
        mm128<<<RB, 256, 0, stream>>>(aggR, sr_Wl + wOff, sr_b + bOff, invR, nxr, NREG, 0);
        mm128<<<RB, 256, 0, stream>>>(cxr, sr_Wr + wOff, nullptr, nullptr, nxr, NREG, 1);

        // gcn self-loop + gcn bias, then edge scatter
        selfloop_bias<<<(NREG * 32 + 255) / 256, 256, 0, stream>>>(nxr, xw, dis, gcn_b + bOff, NREG);
        gcn_scatter<<<EB32, 256, 0, stream>>>(xw, ei_fc, ei_fc + NEDGE, dis, nxr, NEDGE);

        cxs = nxs;
        cxr = nxr;
    }

    // output projections: d_out = [out_subject (NSUB*2) | out_region (NREG*2)]
    float* outp = (float*)d_out;
    lin_out<<<(NSUB + 255) / 256, 256, 0, stream>>>(cxs, lsW, lsb, outp, NSUB);
    lin_out<<<(NREG + 255) / 256, 256, 0, stream>>>(cxr, lrW, lrb, outp + (size_t)NSUB * NOUT, NREG);
}

// Round 2
// 1137.298 us; speedup vs baseline: 6.0010x; 6.0010x over previous
//
#include <hip/hip_runtime.h>

#define NSUB 20000
#define NREG 100000
#define NEDGE 600000
#define DIM 128
#define LAY 2
#define NOUT 2

// ---------------------------------------------------------------------------
// GEMM: out[r, c] (+)= (A[r,:] @ W[:,c]) * scale[r] + bias[c]
// A: [N,128] row-major, W: [128,128] row-major (staged in LDS),
// block = 256 threads, tile = 64 rows x 128 cols, thread = 8 rows x 4 cols.
// NOTE: A and out may alias row-for-row (in-place): each thread reads only
// the rows it writes, and all k-loop loads precede the epilogue stores.
// So no __restrict__ on A/out.
// ---------------------------------------------------------------------------
__global__ __launch_bounds__(256) void mm128(
    const float* A, const float* __restrict__ W,
    const float* __restrict__ bias, const float* __restrict__ scale,
    float* out, int N, int accumulate)
{
    __shared__ float sW[DIM * DIM];   // 64 KB
    const int t = threadIdx.x;
#pragma unroll
    for (int i = 0; i < 16; ++i) {
        const int idx = (i * 256 + t) * 4;
        *(float4*)(sW + idx) = *(const float4*)(W + idx);
    }
    __syncthreads();

    const int tx = t & 31;          // col group
    const int ty = t >> 5;          // row slot (0..7)
    const int c0 = tx * 4;
    const int rowBase = blockIdx.x * 64 + ty * 8;

    const float* pA[8];
#pragma unroll
    for (int i = 0; i < 8; ++i) {
        int r = rowBase + i;
        int rc = r < N ? r : (N - 1);
        pA[i] = A + (size_t)rc * DIM;
    }

    float acc[8][4];
#pragma unroll
    for (int i = 0; i < 8; ++i)
#pragma unroll
        for (int j = 0; j < 4; ++j) acc[i][j] = 0.0f;

    for (int k = 0; k < DIM; k += 4) {
        const float4 w0 = *(const float4*)(sW + (k + 0) * DIM + c0);
        const float4 w1 = *(const float4*)(sW + (k + 1) * DIM + c0);
        const float4 w2 = *(const float4*)(sW + (k + 2) * DIM + c0);
        const float4 w3 = *(const float4*)(sW + (k + 3) * DIM + c0);
#pragma unroll
        for (int i = 0; i < 8; ++i) {
            const float4 a = *(const float4*)(pA[i] + k);
            acc[i][0] += a.x * w0.x + a.y * w1.x + a.z * w2.x + a.w * w3.x;
            acc[i][1] += a.x * w0.y + a.y * w1.y + a.z * w2.y + a.w * w3.y;
            acc[i][2] += a.x * w0.z + a.y * w1.z + a.z * w2.z + a.w * w3.z;
            acc[i][3] += a.x * w0.w + a.y * w1.w + a.z * w2.w + a.w * w3.w;
        }
    }

    float4 bv = make_float4(0.f, 0.f, 0.f, 0.f);
    if (bias) bv = *(const float4*)(bias + c0);

#pragma unroll
    for (int i = 0; i < 8; ++i) {
        const int r = rowBase + i;
        if (r >= N) continue;
        const float s = scale ? scale[r] : 1.0f;
        float4 o;
        o.x = acc[i][0] * s + bv.x;
        o.y = acc[i][1] * s + bv.y;
        o.z = acc[i][2] * s + bv.z;
        o.w = acc[i][3] * s + bv.w;
        float4* po = (float4*)(out + (size_t)r * DIM + c0);
        if (accumulate) {
            float4 p = *po;
            o.x += p.x; o.y += p.y; o.z += p.z; o.w += p.w;
        }
        *po = o;
    }
}

// ---------------------------------------------------------------------------
// CSR build: int-atomic count -> two-level scan -> atomic-cursor fill
// ---------------------------------------------------------------------------
__global__ void count_int(const int* __restrict__ dst, int* __restrict__ cnt, int E)
{
    const int e = blockIdx.x * 256 + threadIdx.x;
    if (e < E) atomicAdd(&cnt[dst[e]], 1);
}

__global__ void scan_block(const int* __restrict__ in, int* __restrict__ incl,
                           int* __restrict__ partial, int n)
{
    __shared__ int s[256];
    const int t = threadIdx.x;
    const int i = blockIdx.x * 256 + t;
    s[t] = (i < n) ? in[i] : 0;
    __syncthreads();
#pragma unroll
    for (int off = 1; off < 256; off <<= 1) {
        const int u = (t >= off) ? s[t - off] : 0;
        __syncthreads();
        s[t] += u;
        __syncthreads();
    }
    if (i < n) incl[i] = s[t];
    if (t == 255) partial[blockIdx.x] = s[255];
}

__global__ void scan_partials(int* __restrict__ partial, int nb)
{
    __shared__ int s[512];
    const int t = threadIdx.x;
    s[t] = (t < nb) ? partial[t] : 0;
    __syncthreads();
#pragma unroll
    for (int off = 1; off < 512; off <<= 1) {
        const int u = (t >= off) ? s[t - off] : 0;
        __syncthreads();
        s[t] += u;
        __syncthreads();
    }
    if (t < nb) partial[t] = s[t];
}

__global__ void make_offsets(const int* __restrict__ incl, const int* __restrict__ partial,
                             int* __restrict__ off, int n)
{
    const int i = blockIdx.x * 256 + threadIdx.x;
    if (i >= n) return;
    const int b = i >> 8;
    const int add = (b > 0) ? partial[b - 1] : 0;
    off[i + 1] = incl[i] + add;
    if (i == 0) off[0] = 0;
}

__global__ void csr_fill(const int* __restrict__ src, const int* __restrict__ dst,
                         const int* __restrict__ off, int* __restrict__ cur,
                         int* __restrict__ csr, int E)
{
    const int e = blockIdx.x * 256 + threadIdx.x;
    if (e >= E) return;
    const int d = dst[e];
    const int slot = off[d] + atomicAdd(&cur[d], 1);
    csr[slot] = src[e];
}

// derived per-node scalars from CSR offsets
__global__ void inv_count(const int* __restrict__ off, float* __restrict__ out, int n)
{
    const int i = blockIdx.x * 256 + threadIdx.x;
    if (i < n) {
        const int c = off[i + 1] - off[i];
        out[i] = 1.0f / fmaxf((float)c, 1.0f);
    }
}

__global__ void gcn_dis(const int* __restrict__ off, float* __restrict__ out, int n)
{
    const int i = blockIdx.x * 256 + threadIdx.x;
    if (i < n) {
        const int c = off[i + 1] - off[i];
        out[i] = rsqrtf((float)(c + 1));   // +1 self loop; deg >= 1 always
    }
}

// ---------------------------------------------------------------------------
// Gathers: 32 lanes per destination row, float4 per lane.
// ---------------------------------------------------------------------------
__global__ __launch_bounds__(256) void gather_sum(
    const float* __restrict__ feat, const int* __restrict__ off,
    const int* __restrict__ csr, float* __restrict__ out, int N)
{
    const int tid = blockIdx.x * 256 + threadIdx.x;
    const int g = tid >> 5;
    if (g >= N) return;
    const int c0 = (tid & 31) * 4;
    const int j1 = off[g + 1];
    float4 acc = make_float4(0.f, 0.f, 0.f, 0.f);
    for (int j = off[g]; j < j1; ++j) {
        const int s = csr[j];
        const float4 v = *(const float4*)(feat + (size_t)s * DIM + c0);
        acc.x += v.x; acc.y += v.y; acc.z += v.z; acc.w += v.w;
    }
    *(float4*)(out + (size_t)g * DIM + c0) = acc;
}

// out[d,:] += dis[d]*( sum_s dis[s]*xw[s,:] + dis[d]*xw[d,:] ) + b[:]
__global__ __launch_bounds__(256) void gcn_gather(
    const float* __restrict__ xw, const int* __restrict__ off,
    const int* __restrict__ csr, const float* __restrict__ dis,
    const float* __restrict__ gb, float* __restrict__ out, int N)
{
    const int tid = blockIdx.x * 256 + threadIdx.x;
    const int g = tid >> 5;
    if (g >= N) return;
    const int c0 = (tid & 31) * 4;
    const int j1 = off[g + 1];
    float4 acc = make_float4(0.f, 0.f, 0.f, 0.f);
    for (int j = off[g]; j < j1; ++j) {
        const int s = csr[j];
        const float w = dis[s];
        const float4 v = *(const float4*)(xw + (size_t)s * DIM + c0);
        acc.x += w * v.x; acc.y += w * v.y; acc.z += w * v.z; acc.w += w * v.w;
    }
    const float dd = dis[g];
    const float4 sf = *(const float4*)(xw + (size_t)g * DIM + c0);
    const float4 b  = *(const float4*)(gb + c0);
    float4 o = *(float4*)(out + (size_t)g * DIM + c0);
    o.x += dd * (acc.x + dd * sf.x) + b.x;
    o.y += dd * (acc.y + dd * sf.y) + b.y;
    o.z += dd * (acc.z + dd * sf.z) + b.z;
    o.w += dd * (acc.w + dd * sf.w) + b.w;
    *(float4*)(out + (size_t)g * DIM + c0) = o;
}

// out[r, 0:2] = X[r,:] @ W[128,2] + b[2]
__global__ void lin_out(const float* __restrict__ X, const float* __restrict__ W,
                        const float* __restrict__ b, float* __restrict__ out, int N)
{
    const int r = blockIdx.x * 256 + threadIdx.x;
    if (r >= N) return;
    float a0 = b[0], a1 = b[1];
    const float* xr = X + (size_t)r * DIM;
#pragma unroll 8
    for (int k = 0; k < DIM; k += 4) {
        const float4 x = *(const float4*)(xr + k);
        a0 += x.x * W[(k + 0) * 2 + 0] + x.y * W[(k + 1) * 2 + 0] +
              x.z * W[(k + 2) * 2 + 0] + x.w * W[(k + 3) * 2 + 0];
        a1 += x.x * W[(k + 0) * 2 + 1] + x.y * W[(k + 1) * 2 + 1] +
              x.z * W[(k + 2) * 2 + 1] + x.w * W[(k + 3) * 2 + 1];
    }
    out[(size_t)r * 2 + 0] = a0;
    out[(size_t)r * 2 + 1] = a1;
}

extern "C" void kernel_launch(void* const* d_in, const int* in_sizes, int n_in,
                              void* d_out, int out_size, void* d_ws, size_t ws_size,
                              hipStream_t stream)
{
    const float* x_subject = (const float*)d_in[0];
    const float* x_region  = (const float*)d_in[1];
    const int*   ei_hr     = (const int*)d_in[2];   // [2,E] row0=subj src, row1=reg dst
    const int*   ei_rev    = (const int*)d_in[3];   // [2,E] row0=reg src, row1=subj dst
    const int*   ei_fc     = (const int*)d_in[4];   // [2,E] region-region
    const float* sr_Wl = (const float*)d_in[5];
    const float* sr_Wr = (const float*)d_in[6];
    const float* sr_b  = (const float*)d_in[7];
    const float* rs_Wl = (const float*)d_in[8];
    const float* rs_Wr = (const float*)d_in[9];
    const float* rs_b  = (const float*)d_in[10];
    const float* gcn_W = (const float*)d_in[11];
    const float* gcn_b = (const float*)d_in[12];
    const float* lsW   = (const float*)d_in[13];
    const float* lsb   = (const float*)d_in[14];
    const float* lrW   = (const float*)d_in[15];
    const float* lrb   = (const float*)d_in[16];

    // ---- workspace layout (floats first: all feature arrays multiple of 128)
    float* p = (float*)d_ws;
    float* xsA  = p; p += (size_t)NSUB * DIM;   // layer-1 subject out
    float* xrA  = p; p += (size_t)NREG * DIM;   // layer-1 region out
    float* aggS = p; p += (size_t)NSUB * DIM;   // subject agg; layer-2 subject out (in-place)
    float* aggR = p; p += (size_t)NREG * DIM;   // region agg;  layer-2 region out (in-place)
    float* xw   = p; p += (size_t)NREG * DIM;
    float* invS = p; p += NSUB;
    float* invR = p; p += NREG;
    float* dis  = p; p += NREG;
    int* ip = (int*)p;
    int* offRev = ip; ip += NSUB + 1;
    int* offHr  = ip; ip += NREG + 1;
    int* offFc  = ip; ip += NREG + 1;
    int* csrRev = ip; ip += NEDGE;
    int* csrHr  = ip; ip += NEDGE;
    int* csrFc  = ip; ip += NEDGE;
    int* tmp    = ip; ip += NREG;      // count, then cursor
    int* incl   = ip; ip += NREG;
    int* partial = ip; ip += 512;

    const int EB  = (NEDGE + 255) / 256;
    const int nbS = (NSUB + 255) / 256;
    const int nbR = (NREG + 255) / 256;

    // ---- build CSR for the three edge types (structure reused across layers)
    struct { const int* src; const int* dst; int n; int nb; int* off; int* csr; } et[3] = {
        { ei_rev,           ei_rev + NEDGE, NSUB, nbS, offRev, csrRev },
        { ei_hr,            ei_hr  + NEDGE, NREG, nbR, offHr,  csrHr  },
        { ei_fc,            ei_fc  + NEDGE, NREG, nbR, offFc,  csrFc  },
    };
    for (int i = 0; i < 3; ++i) {
        hipMemsetAsync(tmp, 0, et[i].n * sizeof(int), stream);
        count_int<<<EB, 256, 0, stream>>>(et[i].dst, tmp, NEDGE);
        scan_block<<<et[i].nb, 256, 0, stream>>>(tmp, incl, partial, et[i].n);
        scan_partials<<<1, 512, 0, stream>>>(partial, et[i].nb);
        make_offsets<<<et[i].nb, 256, 0, stream>>>(incl, partial, et[i].off, et[i].n);
        hipMemsetAsync(tmp, 0, et[i].n * sizeof(int), stream);
        csr_fill<<<EB, 256, 0, stream>>>(et[i].src, et[i].dst, et[i].off, tmp, et[i].csr, NEDGE);
    }
    inv_count<<<nbS, 256, 0, stream>>>(offRev, invS, NSUB);
    inv_count<<<nbR, 256, 0, stream>>>(offHr, invR, NREG);
    gcn_dis<<<nbR, 256, 0, stream>>>(offFc, dis, NREG);

    const float* cxs = x_subject;
    const float* cxr = x_region;
    float* nxs_l[2] = { xsA, aggS };   // layer-2 outputs reuse agg buffers in-place
    float* nxr_l[2] = { xrA, aggR };
    const int SB = (NSUB + 63) / 64;
    const int RB = (NREG + 63) / 64;
    const int GS = (NSUB * 32 + 255) / 256;
    const int GR = (NREG * 32 + 255) / 256;

    for (int l = 0; l < LAY; ++l) {
        float* nxs = nxs_l[l];
        float* nxr = nxr_l[l];
        const size_t wOff = (size_t)l * DIM * DIM;
        const size_t bOff = (size_t)l * DIM;

        // segment sums via CSR gather (mean deferred to GEMM row-scale)
        gather_sum<<<GS, 256, 0, stream>>>(cxr, offRev, csrRev, aggS, NSUB);
        gather_sum<<<GR, 256, 0, stream>>>(cxs, offHr, csrHr, aggR, NREG);

        // new_s = mean_s @ rs_Wl + xs @ rs_Wr + rs_b
        mm128<<<SB, 256, 0, stream>>>(aggS, rs_Wl + wOff, rs_b + bOff, invS, nxs, NSUB, 0);
        mm128<<<SB, 256, 0, stream>>>(cxs, rs_Wr + wOff, nullptr, nullptr, nxs, NSUB, 1);

        // GCN: xw = xr @ gcn_W
        mm128<<<RB, 256, 0, stream>>>(cxr, gcn_W + wOff, nullptr, nullptr, xw, NREG, 0);

        // new_r = mean_r @ sr_Wl + xr @ sr_Wr + sr_b
        mm128<<<RB, 256, 0, stream>>>(aggR, sr_Wl + wOff, sr_b + bOff, invR, nxr, NREG, 0);
        mm128<<<RB, 256, 0, stream>>>(cxr, sr_Wr + wOff, nullptr, nullptr, nxr, NREG, 1);

        // GCN edge gather + self loop + bias, accumulated into nxr
        gcn_gather<<<GR, 256, 0, stream>>>(xw, offFc, csrFc, dis, gcn_b + bOff, nxr, NREG);

        cxs = nxs;
        cxr = nxr;
    }

    // output projections: d_out = [out_subject (NSUB*2) | out_region (NREG*2)]
    float* outp = (float*)d_out;
    lin_out<<<(NSUB + 255) / 256, 256, 0, stream>>>(cxs, lsW, lsb, outp, NSUB);
    lin_out<<<(NREG + 255) / 256, 256, 0, stream>>>(cxr, lrW, lrb, outp + (size_t)NSUB * NOUT, NREG);
}

// Round 3
// 624.462 us; speedup vs baseline: 10.9292x; 1.8212x over previous
//
#include <hip/hip_runtime.h>

#define NSUB 20000
#define NREG 100000
#define NEDGE 600000
#define DIM 128
#define LAY 2
#define NOUT 2

typedef __attribute__((ext_vector_type(8))) short bf16x8;
typedef __attribute__((ext_vector_type(8))) unsigned short u16x8;
typedef __attribute__((ext_vector_type(4))) unsigned short u16x4;
typedef __attribute__((ext_vector_type(4))) float f32x4;

__device__ __forceinline__ float bf2f(unsigned short u) {
    return __uint_as_float(((unsigned)u) << 16);
}
__device__ __forceinline__ unsigned short f2bf(float f) {
    unsigned x = __float_as_uint(f);
    unsigned r = ((x >> 16) & 1u) + 0x7fffu;   // RNE
    return (unsigned short)((x + r) >> 16);
}

// ---------------------------------------------------------------------------
// fp32 -> bf16 bulk convert (n multiple of 4)
// ---------------------------------------------------------------------------
__global__ void cvt_f32_bf16(const float* __restrict__ in, unsigned short* __restrict__ out, int n)
{
    const int base = (blockIdx.x * 256 + threadIdx.x) * 4;
    if (base >= n) return;
    const float4 v = *(const float4*)(in + base);
    u16x4 o; o[0] = f2bf(v.x); o[1] = f2bf(v.y); o[2] = f2bf(v.z); o[3] = f2bf(v.w);
    *(u16x4*)(out + base) = o;
}

// ---------------------------------------------------------------------------
// Pack weight matrices [nmats][128][128] (k-major) into MFMA B-fragment layout:
// frag f = tile_n*4 + kstep; P[m][(f*64+lane)*8 + j] = W[k0+(lane>>4)*8+j][n0+(lane&15)]
// ---------------------------------------------------------------------------
__global__ void pack_w(const float* __restrict__ W, unsigned short* __restrict__ P, int nmats)
{
    const int tid = blockIdx.x * 256 + threadIdx.x;
    if (tid >= nmats * 2048) return;
    const int m = tid >> 11;
    const int rem = tid & 2047;
    const int f = rem >> 6, l = rem & 63;
    const int n0 = (f >> 2) * 16, k0 = (f & 3) * 32;
    const float* Wm = W + (size_t)m * DIM * DIM;
    unsigned short* Pm = P + (size_t)m * 32 * 512 + ((size_t)f * 64 + l) * 8;
    const int kb = k0 + (l >> 4) * 8, n = n0 + (l & 15);
#pragma unroll
    for (int j = 0; j < 8; ++j) Pm[j] = f2bf(Wm[(kb + j) * DIM + n]);
}

// ---------------------------------------------------------------------------
// MFMA GEMMs: block=256 (4 waves), 64 rows/block (16/wave), 128 cols.
// A bf16 row-major [M][128]; W pre-packed fragments; fp32 accumulate.
// ---------------------------------------------------------------------------

// out = A @ W   (bf16 out)
__global__ __launch_bounds__(256) void gemm1(
    const unsigned short* __restrict__ A, const unsigned short* __restrict__ Wp,
    unsigned short* __restrict__ out, int M)
{
    const int t = threadIdx.x, wave = t >> 6, lane = t & 63;
    const int rowBase = blockIdx.x * 64 + wave * 16;
    int arow = rowBase + (lane & 15);
    if (arow >= M) arow = M - 1;
    const bf16x8* Ap = (const bf16x8*)(A + (size_t)arow * DIM + (lane >> 4) * 8);
    const bf16x8* Bp = (const bf16x8*)Wp;
    f32x4 acc[8] = {};
#pragma unroll
    for (int ks = 0; ks < 4; ++ks) {
        const bf16x8 a = Ap[ks * 4];
#pragma unroll
        for (int tn = 0; tn < 8; ++tn) {
            const bf16x8 b = Bp[(tn * 4 + ks) * 64 + lane];
            acc[tn] = __builtin_amdgcn_mfma_f32_16x16x32_bf16(a, b, acc[tn], 0, 0, 0);
        }
    }
    const int col0 = lane & 15;
    const int rbase = rowBase + (lane >> 4) * 4;
#pragma unroll
    for (int tn = 0; tn < 8; ++tn)
#pragma unroll
        for (int r = 0; r < 4; ++r) {
            const int row = rbase + r;
            if (row < M) out[(size_t)row * DIM + tn * 16 + col0] = f2bf(acc[tn][r]);
        }
}

// out = A0 @ W0 + A1 @ W1 + bias   (subject update)
__global__ __launch_bounds__(256) void gemm2(
    const unsigned short* __restrict__ A0, const unsigned short* __restrict__ Wp0,
    const unsigned short* __restrict__ A1, const unsigned short* __restrict__ Wp1,
    const float* __restrict__ bias, unsigned short* __restrict__ out, int M)
{
    const int t = threadIdx.x, wave = t >> 6, lane = t & 63;
    const int rowBase = blockIdx.x * 64 + wave * 16;
    int arow = rowBase + (lane & 15);
    if (arow >= M) arow = M - 1;
    const bf16x8* Ap0 = (const bf16x8*)(A0 + (size_t)arow * DIM + (lane >> 4) * 8);
    const bf16x8* Ap1 = (const bf16x8*)(A1 + (size_t)arow * DIM + (lane >> 4) * 8);
    const bf16x8* Bp0 = (const bf16x8*)Wp0;
    const bf16x8* Bp1 = (const bf16x8*)Wp1;
    f32x4 acc[8] = {};
#pragma unroll
    for (int ks = 0; ks < 4; ++ks) {
        const bf16x8 a0 = Ap0[ks * 4];
        const bf16x8 a1 = Ap1[ks * 4];
#pragma unroll
        for (int tn = 0; tn < 8; ++tn) {
            acc[tn] = __builtin_amdgcn_mfma_f32_16x16x32_bf16(a0, Bp0[(tn * 4 + ks) * 64 + lane], acc[tn], 0, 0, 0);
            acc[tn] = __builtin_amdgcn_mfma_f32_16x16x32_bf16(a1, Bp1[(tn * 4 + ks) * 64 + lane], acc[tn], 0, 0, 0);
        }
    }
    const int col0 = lane & 15;
    const int rbase = rowBase + (lane >> 4) * 4;
#pragma unroll
    for (int tn = 0; tn < 8; ++tn) {
        const float bv = bias[tn * 16 + col0];
#pragma unroll
        for (int r = 0; r < 4; ++r) {
            const int row = rbase + r;
            if (row < M) out[(size_t)row * DIM + tn * 16 + col0] = f2bf(acc[tn][r] + bv);
        }
    }
}

// region update: outMain = A@WpR + bR + bG + agg + dis^2*(A@WpG);  outXw = A@WpG
__global__ __launch_bounds__(256) void gemmR(
    const unsigned short* __restrict__ A,
    const unsigned short* __restrict__ WpR, const unsigned short* __restrict__ WpG,
    const float* __restrict__ bR, const float* __restrict__ bG,
    const unsigned short* __restrict__ agg, const float* __restrict__ dis,
    unsigned short* __restrict__ outMain, unsigned short* __restrict__ outXw, int M)
{
    const int t = threadIdx.x, wave = t >> 6, lane = t & 63;
    const int rowBase = blockIdx.x * 64 + wave * 16;
    int arow = rowBase + (lane & 15);
    if (arow >= M) arow = M - 1;
    const bf16x8* Ap = (const bf16x8*)(A + (size_t)arow * DIM + (lane >> 4) * 8);
    const bf16x8* BpR = (const bf16x8*)WpR;
    const bf16x8* BpG = (const bf16x8*)WpG;
    f32x4 accA[8] = {};
    f32x4 accB[8] = {};
#pragma unroll
    for (int ks = 0; ks < 4; ++ks) {
        const bf16x8 a = Ap[ks * 4];
#pragma unroll
        for (int tn = 0; tn < 8; ++tn) {
            accA[tn] = __builtin_amdgcn_mfma_f32_16x16x32_bf16(a, BpR[(tn * 4 + ks) * 64 + lane], accA[tn], 0, 0, 0);
            accB[tn] = __builtin_amdgcn_mfma_f32_16x16x32_bf16(a, BpG[(tn * 4 + ks) * 64 + lane], accB[tn], 0, 0, 0);
        }
    }
    const int col0 = lane & 15;
    const int rbase = rowBase + (lane >> 4) * 4;
    float dd[4];
#pragma unroll
    for (int r = 0; r < 4; ++r) {
        int row = rbase + r;
        dd[r] = (row < M) ? dis[row] : 0.0f;
    }
#pragma unroll
    for (int tn = 0; tn < 8; ++tn) {
        const int col = tn * 16 + col0;
        const float bv = bR[col] + bG[col];
#pragma unroll
        for (int r = 0; r < 4; ++r) {
            const int row = rbase + r;
            if (row >= M) continue;
            const float xwv = accB[tn][r];
            outXw[(size_t)row * DIM + col] = f2bf(xwv);
            const float v = accA[tn][r] + bv + bf2f(agg[(size_t)row * DIM + col]) + dd[r] * dd[r] * xwv;
            outMain[(size_t)row * DIM + col] = f2bf(v);
        }
    }
}

// ---------------------------------------------------------------------------
// CSR build: int-atomic count -> two-level scan -> atomic-cursor fill
// ---------------------------------------------------------------------------
__global__ void count_int(const int* __restrict__ dst, int* __restrict__ cnt, int E)
{
    const int e = blockIdx.x * 256 + threadIdx.x;
    if (e < E) atomicAdd(&cnt[dst[e]], 1);
}

__global__ void scan_block(const int* __restrict__ in, int* __restrict__ incl,
                           int* __restrict__ partial, int n)
{
    __shared__ int s[256];
    const int t = threadIdx.x;
    const int i = blockIdx.x * 256 + t;
    s[t] = (i < n) ? in[i] : 0;
    __syncthreads();
#pragma unroll
    for (int off = 1; off < 256; off <<= 1) {
        const int u = (t >= off) ? s[t - off] : 0;
        __syncthreads();
        s[t] += u;
        __syncthreads();
    }
    if (i < n) incl[i] = s[t];
    if (t == 255) partial[blockIdx.x] = s[255];
}

__global__ void scan_partials(int* __restrict__ partial, int nb)
{
    __shared__ int s[512];
    const int t = threadIdx.x;
    s[t] = (t < nb) ? partial[t] : 0;
    __syncthreads();
#pragma unroll
    for (int off = 1; off < 512; off <<= 1) {
        const int u = (t >= off) ? s[t - off] : 0;
        __syncthreads();
        s[t] += u;
        __syncthreads();
    }
    if (t < nb) partial[t] = s[t];
}

__global__ void make_offsets(const int* __restrict__ incl, const int* __restrict__ partial,
                             int* __restrict__ off, int n)
{
    const int i = blockIdx.x * 256 + threadIdx.x;
    if (i >= n) return;
    const int b = i >> 8;
    const int add = (b > 0) ? partial[b - 1] : 0;
    off[i + 1] = incl[i] + add;
    if (i == 0) off[0] = 0;
}

__global__ void csr_fill(const int* __restrict__ src, const int* __restrict__ dst,
                         const int* __restrict__ off, int* __restrict__ cur,
                         int* __restrict__ csr, int E)
{
    const int e = blockIdx.x * 256 + threadIdx.x;
    if (e >= E) return;
    const int d = dst[e];
    const int slot = off[d] + atomicAdd(&cur[d], 1);
    csr[slot] = src[e];
}

__global__ void inv_count(const int* __restrict__ off, float* __restrict__ out, int n)
{
    const int i = blockIdx.x * 256 + threadIdx.x;
    if (i < n) {
        const int c = off[i + 1] - off[i];
        out[i] = 1.0f / fmaxf((float)c, 1.0f);
    }
}

__global__ void gcn_dis(const int* __restrict__ off, float* __restrict__ out, int n)
{
    const int i = blockIdx.x * 256 + threadIdx.x;
    if (i < n) {
        const int c = off[i + 1] - off[i];
        out[i] = rsqrtf((float)(c + 1));   // +1 self loop
    }
}

// ---------------------------------------------------------------------------
// Gathers, bf16 features: 16 lanes/row x 16B.
// ---------------------------------------------------------------------------
// out[g,:] = scale[g] * sum_{s in csr[g]} feat[s,:]
__global__ __launch_bounds__(256) void gather_mean(
    const unsigned short* __restrict__ feat, const int* __restrict__ off,
    const int* __restrict__ csr, const float* __restrict__ scale,
    unsigned short* __restrict__ out, int N)
{
    const int tid = blockIdx.x * 256 + threadIdx.x;
    const int g = tid >> 4;
    if (g >= N) return;
    const int c0 = (tid & 15) * 8;
    const int j1 = off[g + 1];
    float acc[8] = {0, 0, 0, 0, 0, 0, 0, 0};
    for (int j = off[g]; j < j1; ++j) {
        const u16x8 v = *(const u16x8*)(feat + (size_t)csr[j] * DIM + c0);
#pragma unroll
        for (int i = 0; i < 8; ++i) acc[i] += bf2f(v[i]);
    }
    const float s = scale[g];
    u16x8 o;
#pragma unroll
    for (int i = 0; i < 8; ++i) o[i] = f2bf(acc[i] * s);
    *(u16x8*)(out + (size_t)g * DIM + c0) = o;
}

// io[g,:] += dis[g] * sum_{s} dis[s]*xw[s,:]
__global__ __launch_bounds__(256) void gcn_gather(
    const unsigned short* __restrict__ xw, const int* __restrict__ off,
    const int* __restrict__ csr, const float* __restrict__ dis,
    unsigned short* __restrict__ io, int N)
{
    const int tid = blockIdx.x * 256 + threadIdx.x;
    const int g = tid >> 4;
    if (g >= N) return;
    const int c0 = (tid & 15) * 8;
    const int j1 = off[g + 1];
    float acc[8] = {0, 0, 0, 0, 0, 0, 0, 0};
    for (int j = off[g]; j < j1; ++j) {
        const int s = csr[j];
        const float w = dis[s];
        const u16x8 v = *(const u16x8*)(xw + (size_t)s * DIM + c0);
#pragma unroll
        for (int i = 0; i < 8; ++i) acc[i] += w * bf2f(v[i]);
    }
    const float dd = dis[g];
    const u16x8 cur = *(const u16x8*)(io + (size_t)g * DIM + c0);
    u16x8 o;
#pragma unroll
    for (int i = 0; i < 8; ++i) o[i] = f2bf(bf2f(cur[i]) + dd * acc[i]);
    *(u16x8*)(io + (size_t)g * DIM + c0) = o;
}

// out[r, 0:2] = X[r,:] @ W[128,2] + b[2]  (X bf16)
__global__ void lin_out_bf(const unsigned short* __restrict__ X, const float* __restrict__ W,
                           const float* __restrict__ b, float* __restrict__ out, int N)
{
    const int r = blockIdx.x * 256 + threadIdx.x;
    if (r >= N) return;
    float a0 = b[0], a1 = b[1];
    const unsigned short* xr = X + (size_t)r * DIM;
#pragma unroll
    for (int k = 0; k < DIM; k += 8) {
        const u16x8 v = *(const u16x8*)(xr + k);
#pragma unroll
        for (int i = 0; i < 8; ++i) {
            const float x = bf2f(v[i]);
            a0 += x * W[(k + i) * 2 + 0];
            a1 += x * W[(k + i) * 2 + 1];
        }
    }
    out[(size_t)r * 2 + 0] = a0;
    out[(size_t)r * 2 + 1] = a1;
}

extern "C" void kernel_launch(void* const* d_in, const int* in_sizes, int n_in,
                              void* d_out, int out_size, void* d_ws, size_t ws_size,
                              hipStream_t stream)
{
    const float* x_subject = (const float*)d_in[0];
    const float* x_region  = (const float*)d_in[1];
    const int*   ei_hr     = (const int*)d_in[2];
    const int*   ei_rev    = (const int*)d_in[3];
    const int*   ei_fc     = (const int*)d_in[4];
    const float* sr_Wl = (const float*)d_in[5];
    const float* sr_Wr = (const float*)d_in[6];
    const float* sr_b  = (const float*)d_in[7];
    const float* rs_Wl = (const float*)d_in[8];
    const float* rs_Wr = (const float*)d_in[9];
    const float* rs_b  = (const float*)d_in[10];
    const float* gcn_W = (const float*)d_in[11];
    const float* gcn_b = (const float*)d_in[12];
    const float* lsW   = (const float*)d_in[13];
    const float* lsb   = (const float*)d_in[14];
    const float* lrW   = (const float*)d_in[15];
    const float* lrb   = (const float*)d_in[16];

    // ---- workspace layout: fp32 | bf16 (all 256B-aligned) | int32
    float* fp = (float*)d_ws;
    float* invS = fp; fp += NSUB;
    float* invR = fp; fp += NREG;
    float* dis  = fp; fp += NREG;
    unsigned short* up = (unsigned short*)fp;
    unsigned short* xsA  = up; up += (size_t)NSUB * DIM;
    unsigned short* xsB  = up; up += (size_t)NSUB * DIM;
    unsigned short* txS  = up; up += (size_t)NSUB * DIM;
    unsigned short* aggS = up; up += (size_t)NSUB * DIM;
    unsigned short* xrA  = up; up += (size_t)NREG * DIM;
    unsigned short* xrB  = up; up += (size_t)NREG * DIM;
    unsigned short* aggR = up; up += (size_t)NREG * DIM;
    unsigned short* xw   = up; up += (size_t)NREG * DIM;
    unsigned short* pSrWl = up; up += (size_t)LAY * 16384;
    unsigned short* pSrWr = up; up += (size_t)LAY * 16384;
    unsigned short* pRsWl = up; up += (size_t)LAY * 16384;
    unsigned short* pRsWr = up; up += (size_t)LAY * 16384;
    unsigned short* pGcn  = up; up += (size_t)LAY * 16384;
    int* ip = (int*)up;
    int* offRev = ip; ip += NSUB + 1;
    int* offHr  = ip; ip += NREG + 1;
    int* offFc  = ip; ip += NREG + 1;
    int* csrRev = ip; ip += NEDGE;
    int* csrHr  = ip; ip += NEDGE;
    int* csrFc  = ip; ip += NEDGE;
    int* tmp    = ip; ip += NREG;
    int* incl   = ip; ip += NREG;
    int* partial = ip; ip += 512;

    const int EB  = (NEDGE + 255) / 256;
    const int nbS = (NSUB + 255) / 256;
    const int nbR = (NREG + 255) / 256;

    // ---- CSR build (edge structure reused across layers)
    struct { const int* src; const int* dst; int n; int nb; int* off; int* csr; } et[3] = {
        { ei_rev, ei_rev + NEDGE, NSUB, nbS, offRev, csrRev },
        { ei_hr,  ei_hr  + NEDGE, NREG, nbR, offHr,  csrHr  },
        { ei_fc,  ei_fc  + NEDGE, NREG, nbR, offFc,  csrFc  },
    };
    for (int i = 0; i < 3; ++i) {
        hipMemsetAsync(tmp, 0, et[i].n * sizeof(int), stream);
        count_int<<<EB, 256, 0, stream>>>(et[i].dst, tmp, NEDGE);
        scan_block<<<et[i].nb, 256, 0, stream>>>(tmp, incl, partial, et[i].n);
        scan_partials<<<1, 512, 0, stream>>>(partial, et[i].nb);
        make_offsets<<<et[i].nb, 256, 0, stream>>>(incl, partial, et[i].off, et[i].n);
        hipMemsetAsync(tmp, 0, et[i].n * sizeof(int), stream);
        csr_fill<<<EB, 256, 0, stream>>>(et[i].src, et[i].dst, et[i].off, tmp, et[i].csr, NEDGE);
    }
    inv_count<<<nbS, 256, 0, stream>>>(offRev, invS, NSUB);
    inv_count<<<nbR, 256, 0, stream>>>(offHr, invR, NREG);
    gcn_dis<<<nbR, 256, 0, stream>>>(offFc, dis, NREG);

    // ---- weight packing + input conversion
    const int PW = (LAY * 2048 + 255) / 256;
    pack_w<<<PW, 256, 0, stream>>>(sr_Wl, pSrWl, LAY);
    pack_w<<<PW, 256, 0, stream>>>(sr_Wr, pSrWr, LAY);
    pack_w<<<PW, 256, 0, stream>>>(rs_Wl, pRsWl, LAY);
    pack_w<<<PW, 256, 0, stream>>>(rs_Wr, pRsWr, LAY);
    pack_w<<<PW, 256, 0, stream>>>(gcn_W, pGcn, LAY);
    cvt_f32_bf16<<<(NSUB * DIM / 4 + 255) / 256, 256, 0, stream>>>(x_subject, xsA, NSUB * DIM);
    cvt_f32_bf16<<<(NREG * DIM / 4 + 255) / 256, 256, 0, stream>>>(x_region, xrA, NREG * DIM);

    const unsigned short* cxs = xsA;
    const unsigned short* cxr = xrA;
    unsigned short* nxs_l[2] = { xsB, xsA };
    unsigned short* nxr_l[2] = { xrB, xrA };
    const int SGB = (NSUB + 63) / 64;     // gemm blocks, 64 rows each
    const int RGB = (NREG + 63) / 64;
    const int GS = (NSUB * 16 + 255) / 256;  // gather blocks, 16 lanes/row
    const int GR = (NREG * 16 + 255) / 256;

    for (int l = 0; l < LAY; ++l) {
        unsigned short* nxs = nxs_l[l];
        unsigned short* nxr = nxr_l[l];
        const size_t pOff = (size_t)l * 16384;
        const size_t bOff = (size_t)l * DIM;

        // 1) txS = xs @ sr_Wl  (transform-first for hr edges)
        gemm1<<<SGB, 256, 0, stream>>>(cxs, pSrWl + pOff, txS, NSUB);
        // 2) aggR = invR * gather_hr(txS)   (== mean_hr @ sr_Wl)
        gather_mean<<<GR, 256, 0, stream>>>(txS, offHr, csrHr, invR, aggR, NREG);
        // 3) aggS = invS * gather_rev(xr)
        gather_mean<<<GS, 256, 0, stream>>>(cxr, offRev, csrRev, invS, aggS, NSUB);
        // 4) xs_next = aggS @ rs_Wl + xs @ rs_Wr + rs_b
        gemm2<<<SGB, 256, 0, stream>>>(cxs, pRsWr + pOff, aggS, pRsWl + pOff,
                                       rs_b + bOff, nxs, NSUB);
        // 5) region GEMM: nxr = xr@sr_Wr + sr_b + gcn_b + aggR + dis^2*xw ; xw = xr@gcn_W
        gemmR<<<RGB, 256, 0, stream>>>(cxr, pSrWr + pOff, pGcn + pOff,
                                       sr_b + bOff, gcn_b + bOff, aggR, dis, nxr, xw, NREG);
        // 6) nxr += dis[d] * gather_fc(dis[s]*xw[s])
        gcn_gather<<<GR, 256, 0, stream>>>(xw, offFc, csrFc, dis, nxr, NREG);

        cxs = nxs;
        cxr = nxr;
    }

    // ---- output projections
    float* outp = (float*)d_out;
    lin_out_bf<<<(NSUB + 255) / 256, 256, 0, stream>>>(cxs, lsW, lsb, outp, NSUB);
    lin_out_bf<<<(NREG + 255) / 256, 256, 0, stream>>>(cxr, lrW, lrb, outp + (size_t)NSUB * NOUT, NREG);
}

// Round 4
// 547.670 us; speedup vs baseline: 12.4617x; 1.1402x over previous
//
#include <hip/hip_runtime.h>

#define NSUB 20000
#define NREG 100000
#define NEDGE 600000
#define DIM 128
#define LAY 2
#define NOUT 2

#define EB 2344              // edge blocks (256 thr): 2344*256 >= 600000
#define NBS 79               // node scan blocks, subject (79*256=20224)
#define NBR 391              // node scan blocks, region  (391*256=100096)
#define PS (NBS * 256)       // padded subject count segment
#define PR (NBR * 256)       // padded region count segment
#define CNT_ALL (PS + 2 * PR)  // 220416 = 861*256 exactly
#define NBLK (NBS + 2 * NBR)   // 861

typedef __attribute__((ext_vector_type(8))) short bf16x8;
typedef __attribute__((ext_vector_type(8))) unsigned short u16x8;
typedef __attribute__((ext_vector_type(4))) unsigned short u16x4;
typedef __attribute__((ext_vector_type(4))) float f32x4;

__device__ __forceinline__ float bf2f(unsigned short u) {
    return __uint_as_float(((unsigned)u) << 16);
}
__device__ __forceinline__ unsigned short f2bf(float f) {
    unsigned x = __float_as_uint(f);
    unsigned r = ((x >> 16) & 1u) + 0x7fffu;   // RNE
    return (unsigned short)((x + r) >> 16);
}

// ---------------------------------------------------------------------------
// Unified MFMA GEMM: out = A0@W0 [+ A1@W1] [+ agg] [+ b0] [+ b1]   (bf16 out)
// block=256 (4 waves), 64 rows/block, 128 cols. Weights pre-packed fragments.
// Epilogue staged through padded LDS -> contiguous 64 B/thread stores.
// ---------------------------------------------------------------------------
__global__ __launch_bounds__(256) void gemm_fused(
    const unsigned short* __restrict__ A0, const unsigned short* __restrict__ Wp0,
    const unsigned short* __restrict__ A1, const unsigned short* __restrict__ Wp1,
    const unsigned short* __restrict__ agg,
    const float* __restrict__ b0, const float* __restrict__ b1,
    unsigned short* __restrict__ out, int M)
{
    __shared__ unsigned short sO[64 * 132];   // padded: row stride 132 u16 (66 dw)
    const int t = threadIdx.x, wave = t >> 6, lane = t & 63;
    const int rowBase = blockIdx.x * 64;
    int arow = rowBase + wave * 16 + (lane & 15);
    if (arow >= M) arow = M - 1;
    const bf16x8* Ap0 = (const bf16x8*)(A0 + (size_t)arow * DIM + (lane >> 4) * 8);
    const bf16x8* Bp0 = (const bf16x8*)Wp0;
    f32x4 acc[8] = {};
    if (A1) {
        const bf16x8* Ap1 = (const bf16x8*)(A1 + (size_t)arow * DIM + (lane >> 4) * 8);
        const bf16x8* Bp1 = (const bf16x8*)Wp1;
#pragma unroll
        for (int ks = 0; ks < 4; ++ks) {
            const bf16x8 a0 = Ap0[ks * 4];
            const bf16x8 a1 = Ap1[ks * 4];
#pragma unroll
            for (int tn = 0; tn < 8; ++tn) {
                acc[tn] = __builtin_amdgcn_mfma_f32_16x16x32_bf16(a0, Bp0[(tn * 4 + ks) * 64 + lane], acc[tn], 0, 0, 0);
                acc[tn] = __builtin_amdgcn_mfma_f32_16x16x32_bf16(a1, Bp1[(tn * 4 + ks) * 64 + lane], acc[tn], 0, 0, 0);
            }
        }
    } else {
#pragma unroll
        for (int ks = 0; ks < 4; ++ks) {
            const bf16x8 a0 = Ap0[ks * 4];
#pragma unroll
            for (int tn = 0; tn < 8; ++tn)
                acc[tn] = __builtin_amdgcn_mfma_f32_16x16x32_bf16(a0, Bp0[(tn * 4 + ks) * 64 + lane], acc[tn], 0, 0, 0);
        }
    }
    // epilogue: bias + agg, store to padded LDS (conflict-free write pattern)
    const int col0 = lane & 15;
    const int lrow0 = wave * 16 + (lane >> 4) * 4;
#pragma unroll
    for (int tn = 0; tn < 8; ++tn) {
        const int col = tn * 16 + col0;
        float bv = 0.0f;
        if (b0) bv += b0[col];
        if (b1) bv += b1[col];
#pragma unroll
        for (int r = 0; r < 4; ++r) {
            float v = acc[tn][r] + bv;
            if (agg) v += bf2f(agg[(size_t)(rowBase + lrow0 + r) * DIM + col]);
            sO[(lrow0 + r) * 132 + col] = f2bf(v);
        }
    }
    __syncthreads();
    // flat contiguous store: thread t -> row t>>2, cols (t&3)*32 .. +31
    const int lr = t >> 2, lc = (t & 3) * 32;
    const int grow = rowBase + lr;
    if (grow < M) {
        unsigned short* po = out + (size_t)grow * DIM + lc;
        const unsigned short* ps = sO + lr * 132 + lc;
#pragma unroll
        for (int j = 0; j < 8; ++j)
            *(u16x4*)(po + j * 4) = *(const u16x4*)(ps + j * 4);
    }
}

// ---------------------------------------------------------------------------
// Batched CSR build over the three edge types in one set of launches.
// Count/cursor/incl arrays are concatenated with 256-aligned segments.
// ---------------------------------------------------------------------------
__global__ void count3(const int* __restrict__ d0, const int* __restrict__ d1,
                       const int* __restrict__ d2, int* __restrict__ cntAll)
{
    const int b = blockIdx.x;
    const int type = b / EB;
    const int e = (b - type * EB) * 256 + threadIdx.x;
    if (e >= NEDGE) return;
    const int* dst = (type == 0) ? d0 : (type == 1) ? d1 : d2;
    const int base = (type == 0) ? 0 : (type == 1) ? PS : PS + PR;
    atomicAdd(&cntAll[base + dst[e]], 1);
}

__global__ void scan3(const int* __restrict__ in, int* __restrict__ incl,
                      int* __restrict__ partial)
{
    __shared__ int s[256];
    const int t = threadIdx.x;
    const int i = blockIdx.x * 256 + t;     // CNT_ALL = 861*256 exactly
    s[t] = in[i];
    __syncthreads();
#pragma unroll
    for (int off = 1; off < 256; off <<= 1) {
        const int u = (t >= off) ? s[t - off] : 0;
        __syncthreads();
        s[t] += u;
        __syncthreads();
    }
    incl[i] = s[t];
    if (t == 255) partial[blockIdx.x] = s[255];
}

__global__ void scan_partials3(int* __restrict__ partial)
{
    const int b = blockIdx.x;
    const int start = (b == 0) ? 0 : (b == 1) ? NBS : NBS + NBR;
    const int len = (b == 0) ? NBS : NBR;
    __shared__ int s[512];
    const int t = threadIdx.x;
    s[t] = (t < len) ? partial[start + t] : 0;
    __syncthreads();
#pragma unroll
    for (int off = 1; off < 512; off <<= 1) {
        const int u = (t >= off) ? s[t - off] : 0;
        __syncthreads();
        s[t] += u;
        __syncthreads();
    }
    if (t < len) partial[start + t] = s[t];
}

__global__ void make_offsets3(const int* __restrict__ incl, const int* __restrict__ partial,
                              int* __restrict__ offRev, int* __restrict__ offHr,
                              int* __restrict__ offFc)
{
    const int b = blockIdx.x, t = threadIdx.x;
    int lb, n, segStart; int* off;
    if (b < NBS)            { lb = b;             n = NSUB; segStart = 0;         off = offRev; }
    else if (b < NBS + NBR) { lb = b - NBS;       n = NREG; segStart = NBS;       off = offHr; }
    else                    { lb = b - NBS - NBR; n = NREG; segStart = NBS + NBR; off = offFc; }
    const int i = lb * 256 + t;
    if (i >= n) return;
    const int add = (lb > 0) ? partial[segStart + lb - 1] : 0;
    off[i + 1] = incl[b * 256 + t] + add;
    if (i == 0) off[0] = 0;
}

__global__ void fill3(const int* __restrict__ s0, const int* __restrict__ d0,
                      const int* __restrict__ s1, const int* __restrict__ d1,
                      const int* __restrict__ s2, const int* __restrict__ d2,
                      const int* __restrict__ offRev, const int* __restrict__ offHr,
                      const int* __restrict__ offFc, int* __restrict__ curAll,
                      int* __restrict__ csrRev, int* __restrict__ csrHr,
                      int* __restrict__ csrFc)
{
    const int b = blockIdx.x;
    const int type = b / EB;
    const int e = (b - type * EB) * 256 + threadIdx.x;
    if (e >= NEDGE) return;
    const int* src = (type == 0) ? s0 : (type == 1) ? s1 : s2;
    const int* dst = (type == 0) ? d0 : (type == 1) ? d1 : d2;
    const int* off = (type == 0) ? offRev : (type == 1) ? offHr : offFc;
    int* csr = (type == 0) ? csrRev : (type == 1) ? csrHr : csrFc;
    const int base = (type == 0) ? 0 : (type == 1) ? PS : PS + PR;
    const int d = dst[e];
    const int slot = off[d] + atomicAdd(&curAll[base + d], 1);
    csr[slot] = src[e];
}

__global__ void derive3(const int* __restrict__ offRev, const int* __restrict__ offHr,
                        const int* __restrict__ offFc, float* __restrict__ invS,
                        float* __restrict__ invR, float* __restrict__ dis)
{
    int i = blockIdx.x * 256 + threadIdx.x;
    if (i < NSUB) {
        const int c = offRev[i + 1] - offRev[i];
        invS[i] = 1.0f / fmaxf((float)c, 1.0f);
        return;
    }
    i -= NSUB;
    if (i < NREG) {
        const int c = offHr[i + 1] - offHr[i];
        invR[i] = 1.0f / fmaxf((float)c, 1.0f);
        return;
    }
    i -= NREG;
    if (i < NREG) {
        const int c = offFc[i + 1] - offFc[i];
        dis[i] = rsqrtf((float)(c + 1));      // +1 self loop
    }
}

// ---------------------------------------------------------------------------
// pack all 5 weight tensors [LAY][128][128] into MFMA B-fragment layout
// ---------------------------------------------------------------------------
__global__ void pack5(const float* __restrict__ w0, const float* __restrict__ w1,
                      const float* __restrict__ w2, const float* __restrict__ w3,
                      const float* __restrict__ w4,
                      unsigned short* __restrict__ p0, unsigned short* __restrict__ p1,
                      unsigned short* __restrict__ p2, unsigned short* __restrict__ p3,
                      unsigned short* __restrict__ p4)
{
    const int tid = blockIdx.x * 256 + threadIdx.x;   // 5*LAY*2048 = 20480
    const int which = tid >> 12;                       // / (LAY*2048)
    const int rem = tid & 4095;
    const float* W = (which == 0) ? w0 : (which == 1) ? w1 : (which == 2) ? w2 : (which == 3) ? w3 : w4;
    unsigned short* P = (which == 0) ? p0 : (which == 1) ? p1 : (which == 2) ? p2 : (which == 3) ? p3 : p4;
    const int m = rem >> 11;
    const int rr = rem & 2047;
    const int f = rr >> 6, l = rr & 63;
    const int n0 = (f >> 2) * 16, k0 = (f & 3) * 32;
    const float* Wm = W + (size_t)m * DIM * DIM;
    unsigned short* Pm = P + (size_t)m * 32 * 512 + ((size_t)f * 64 + l) * 8;
    const int kb = k0 + (l >> 4) * 8, n = n0 + (l & 15);
#pragma unroll
    for (int j = 0; j < 8; ++j) Pm[j] = f2bf(Wm[(kb + j) * DIM + n]);
}

__global__ void cvt2(const float* __restrict__ xs, const float* __restrict__ xr,
                     unsigned short* __restrict__ outS, unsigned short* __restrict__ outR)
{
    const int i = blockIdx.x * 256 + threadIdx.x;
    const int nS = NSUB * DIM / 4;     // 640000 (multiple of 256)
    const float* in;
    unsigned short* out;
    int base;
    if (i < nS) { in = xs; out = outS; base = i * 4; }
    else {
        const int j = i - nS;
        if (j >= NREG * DIM / 4) return;
        in = xr; out = outR; base = j * 4;
    }
    const float4 v = *(const float4*)(in + base);
    u16x4 o; o[0] = f2bf(v.x); o[1] = f2bf(v.y); o[2] = f2bf(v.z); o[3] = f2bf(v.w);
    *(u16x4*)(out + base) = o;
}

// ---------------------------------------------------------------------------
// Merged gathers: 16 lanes/row, u16x8 per lane.
//   g < NREG:  aggR[g] = invR[g] * sum_hr txS[s];  h[g] = dis[g]*sum_fc dis[s]*xr[s] + dis[g]^2*xr[g]
//   g >= NREG: aggS[g-NREG] = invS * sum_rev xr[s]
// (NREG*16 % 64 == 0 -> branch is wave-uniform)
// ---------------------------------------------------------------------------
__global__ __launch_bounds__(256) void gather_all(
    const unsigned short* __restrict__ txS, const unsigned short* __restrict__ xr,
    const int* __restrict__ offHr, const int* __restrict__ csrHr, const float* __restrict__ invR,
    const int* __restrict__ offFc, const int* __restrict__ csrFc, const float* __restrict__ dis,
    const int* __restrict__ offRev, const int* __restrict__ csrRev, const float* __restrict__ invS,
    unsigned short* __restrict__ aggR, unsigned short* __restrict__ h,
    unsigned short* __restrict__ aggS)
{
    const int tid = blockIdx.x * 256 + threadIdx.x;
    const int g = tid >> 4;
    const int c0 = (tid & 15) * 8;
    if (g < NREG) {
        float acc[8] = {0, 0, 0, 0, 0, 0, 0, 0};
        const int j1 = offHr[g + 1];
        for (int j = offHr[g]; j < j1; ++j) {
            const u16x8 v = *(const u16x8*)(txS + (size_t)csrHr[j] * DIM + c0);
#pragma unroll
            for (int i = 0; i < 8; ++i) acc[i] += bf2f(v[i]);
        }
        const float sR = invR[g];
        u16x8 o;
#pragma unroll
        for (int i = 0; i < 8; ++i) o[i] = f2bf(acc[i] * sR);
        *(u16x8*)(aggR + (size_t)g * DIM + c0) = o;

        float a2[8] = {0, 0, 0, 0, 0, 0, 0, 0};
        const int j3 = offFc[g + 1];
        for (int j = offFc[g]; j < j3; ++j) {
            const int s = csrFc[j];
            const float w = dis[s];
            const u16x8 v = *(const u16x8*)(xr + (size_t)s * DIM + c0);
#pragma unroll
            for (int i = 0; i < 8; ++i) a2[i] += w * bf2f(v[i]);
        }
        const float dd = dis[g];
        const u16x8 sf = *(const u16x8*)(xr + (size_t)g * DIM + c0);
        u16x8 oh;
#pragma unroll
        for (int i = 0; i < 8; ++i) oh[i] = f2bf(dd * a2[i] + dd * dd * bf2f(sf[i]));
        *(u16x8*)(h + (size_t)g * DIM + c0) = oh;
    } else {
        const int gs = g - NREG;
        if (gs >= NSUB) return;
        float acc[8] = {0, 0, 0, 0, 0, 0, 0, 0};
        const int j1 = offRev[gs + 1];
        for (int j = offRev[gs]; j < j1; ++j) {
            const u16x8 v = *(const u16x8*)(xr + (size_t)csrRev[j] * DIM + c0);
#pragma unroll
            for (int i = 0; i < 8; ++i) acc[i] += bf2f(v[i]);
        }
        const float sS = invS[gs];
        u16x8 o;
#pragma unroll
        for (int i = 0; i < 8; ++i) o[i] = f2bf(acc[i] * sS);
        *(u16x8*)(aggS + (size_t)gs * DIM + c0) = o;
    }
}

// merged output projections: rows [0,NSUB) subject, [NSUB, NSUB+NREG) region
__global__ void lin2(const unsigned short* __restrict__ XS, const unsigned short* __restrict__ XR,
                     const float* __restrict__ Ws, const float* __restrict__ bs,
                     const float* __restrict__ Wr, const float* __restrict__ br,
                     float* __restrict__ out)
{
    const int r = blockIdx.x * 256 + threadIdx.x;
    if (r >= NSUB + NREG) return;
    const unsigned short* X;
    const float *W, *b;
    size_t row;
    if (r < NSUB) { X = XS; W = Ws; b = bs; row = r; }
    else          { X = XR; W = Wr; b = br; row = r - NSUB; }
    float a0 = b[0], a1 = b[1];
    const unsigned short* xp = X + row * DIM;
#pragma unroll
    for (int k = 0; k < DIM; k += 8) {
        const u16x8 v = *(const u16x8*)(xp + k);
#pragma unroll
        for (int i = 0; i < 8; ++i) {
            const float x = bf2f(v[i]);
            a0 += x * W[(k + i) * 2 + 0];
            a1 += x * W[(k + i) * 2 + 1];
        }
    }
    out[(size_t)r * 2 + 0] = a0;
    out[(size_t)r * 2 + 1] = a1;
}

extern "C" void kernel_launch(void* const* d_in, const int* in_sizes, int n_in,
                              void* d_out, int out_size, void* d_ws, size_t ws_size,
                              hipStream_t stream)
{
    const float* x_subject = (const float*)d_in[0];
    const float* x_region  = (const float*)d_in[1];
    const int*   ei_hr     = (const int*)d_in[2];
    const int*   ei_rev    = (const int*)d_in[3];
    const int*   ei_fc     = (const int*)d_in[4];
    const float* sr_Wl = (const float*)d_in[5];
    const float* sr_Wr = (const float*)d_in[6];
    const float* sr_b  = (const float*)d_in[7];
    const float* rs_Wl = (const float*)d_in[8];
    const float* rs_Wr = (const float*)d_in[9];
    const float* rs_b  = (const float*)d_in[10];
    const float* gcn_W = (const float*)d_in[11];
    const float* gcn_b = (const float*)d_in[12];
    const float* lsW   = (const float*)d_in[13];
    const float* lsb   = (const float*)d_in[14];
    const float* lrW   = (const float*)d_in[15];
    const float* lrb   = (const float*)d_in[16];

    // ---- workspace layout: f32 | bf16 | int32
    float* fp = (float*)d_ws;
    float* invS = fp; fp += NSUB;
    float* invR = fp; fp += NREG;
    float* dis  = fp; fp += NREG;
    unsigned short* up = (unsigned short*)fp;
    unsigned short* xsA  = up; up += (size_t)NSUB * DIM;
    unsigned short* xsB  = up; up += (size_t)NSUB * DIM;
    unsigned short* txS  = up; up += (size_t)NSUB * DIM;
    unsigned short* aggS = up; up += (size_t)NSUB * DIM;
    unsigned short* xrA  = up; up += (size_t)NREG * DIM;
    unsigned short* xrB  = up; up += (size_t)NREG * DIM;
    unsigned short* aggR = up; up += (size_t)NREG * DIM;
    unsigned short* h    = up; up += (size_t)NREG * DIM;
    unsigned short* pSrWl = up; up += (size_t)LAY * 16384;
    unsigned short* pSrWr = up; up += (size_t)LAY * 16384;
    unsigned short* pRsWl = up; up += (size_t)LAY * 16384;
    unsigned short* pRsWr = up; up += (size_t)LAY * 16384;
    unsigned short* pGcn  = up; up += (size_t)LAY * 16384;
    int* ip = (int*)up;
    int* offRev = ip; ip += NSUB + 1;
    int* offHr  = ip; ip += NREG + 1;
    int* offFc  = ip; ip += NREG + 2;   // +1 pad keeps next 8B-aligned
    int* csrRev = ip; ip += NEDGE;
    int* csrHr  = ip; ip += NEDGE;
    int* csrFc  = ip; ip += NEDGE;
    int* cntAll = ip; ip += CNT_ALL;    // cnt + cursor adjacent: single memset
    int* curAll = ip; ip += CNT_ALL;
    int* inclAll = ip; ip += CNT_ALL;
    int* partAll = ip; ip += 1024;

    // ---- CSR build (batched across the 3 edge types)
    hipMemsetAsync(cntAll, 0, 2 * CNT_ALL * sizeof(int), stream);
    count3<<<3 * EB, 256, 0, stream>>>(ei_rev + NEDGE, ei_hr + NEDGE, ei_fc + NEDGE, cntAll);
    scan3<<<NBLK, 256, 0, stream>>>(cntAll, inclAll, partAll);
    scan_partials3<<<3, 512, 0, stream>>>(partAll);
    make_offsets3<<<NBLK, 256, 0, stream>>>(inclAll, partAll, offRev, offHr, offFc);
    fill3<<<3 * EB, 256, 0, stream>>>(ei_rev, ei_rev + NEDGE, ei_hr, ei_hr + NEDGE,
                                      ei_fc, ei_fc + NEDGE, offRev, offHr, offFc,
                                      curAll, csrRev, csrHr, csrFc);
    derive3<<<(NSUB + 2 * NREG + 255) / 256, 256, 0, stream>>>(offRev, offHr, offFc, invS, invR, dis);

    // ---- weight packing + input conversion
    pack5<<<80, 256, 0, stream>>>(sr_Wl, sr_Wr, rs_Wl, rs_Wr, gcn_W,
                                  pSrWl, pSrWr, pRsWl, pRsWr, pGcn);
    cvt2<<<(NSUB + NREG) * DIM / 4 / 256, 256, 0, stream>>>(x_subject, x_region, xsA, xrA);

    const unsigned short* cxs = xsA;
    const unsigned short* cxr = xrA;
    unsigned short* nxs_l[2] = { xsB, xsA };
    unsigned short* nxr_l[2] = { xrB, xrA };
    const int SGB = (NSUB + 63) / 64;
    const int RGB = (NREG + 63) / 64;
    const int GA = ((NREG + NSUB) * 16) / 256;   // 7500 exactly

    for (int l = 0; l < LAY; ++l) {
        unsigned short* nxs = nxs_l[l];
        unsigned short* nxr = nxr_l[l];
        const size_t pOff = (size_t)l * 16384;
        const size_t bOff = (size_t)l * DIM;

        // 1) txS = xs @ sr_Wl   (transform-first for hr edges)
        gemm_fused<<<SGB, 256, 0, stream>>>(cxs, pSrWl + pOff, nullptr, nullptr,
                                            nullptr, nullptr, nullptr, txS, NSUB);
        // 2) aggR = invR*gather_hr(txS); h = GCN-aggregate(xr); aggS = invS*gather_rev(xr)
        gather_all<<<GA, 256, 0, stream>>>(txS, cxr, offHr, csrHr, invR,
                                           offFc, csrFc, dis, offRev, csrRev, invS,
                                           aggR, h, aggS);
        // 3) xs_next = xs @ rs_Wr + aggS @ rs_Wl + rs_b
        gemm_fused<<<SGB, 256, 0, stream>>>(cxs, pRsWr + pOff, aggS, pRsWl + pOff,
                                            nullptr, rs_b + bOff, nullptr, nxs, NSUB);
        // 4) xr_next = xr @ sr_Wr + h @ gcn_W + aggR + sr_b + gcn_b
        gemm_fused<<<RGB, 256, 0, stream>>>(cxr, pSrWr + pOff, h, pGcn + pOff,
                                            aggR, sr_b + bOff, gcn_b + bOff, nxr, NREG);
        cxs = nxs;
        cxr = nxr;
    }

    // ---- output projections
    lin2<<<(NSUB + NREG + 255) / 256, 256, 0, stream>>>(cxs, cxr, lsW, lsb, lrW, lrb,
                                                        (float*)d_out);
}

// Round 5
// 435.112 us; speedup vs baseline: 15.6854x; 1.2587x over previous
//
#include <hip/hip_runtime.h>

#define NSUB 20000
#define NREG 100000
#define NEDGE 600000
#define DIM 128
#define LAY 2
#define NOUT 2

#define EB 2344              // edge blocks (256 thr): 2344*256 >= 600000
#define NBS 79               // node scan blocks, subject (79*256=20224)
#define NBR 391              // node scan blocks, region  (391*256=100096)
#define PS (NBS * 256)       // padded subject count segment
#define PR (NBR * 256)       // padded region count segment
#define CNT_ALL (PS + 2 * PR)  // 220416 = 861*256 exactly
#define NBLK (NBS + 2 * NBR)   // 861

typedef __attribute__((ext_vector_type(8))) short bf16x8;
typedef __attribute__((ext_vector_type(8))) unsigned short u16x8;
typedef __attribute__((ext_vector_type(4))) unsigned short u16x4;
typedef __attribute__((ext_vector_type(4))) float f32x4;

__device__ __forceinline__ float bf2f(unsigned short u) {
    return __uint_as_float(((unsigned)u) << 16);
}
__device__ __forceinline__ unsigned short f2bf(float f) {
    unsigned x = __float_as_uint(f);
    unsigned r = ((x >> 16) & 1u) + 0x7fffu;   // RNE
    return (unsigned short)((x + r) >> 16);
}

// ---------------------------------------------------------------------------
// Shared MFMA GEMM body: acc = A0@W0 [+ A1@W1]; epilogue adds bias/agg,
// stages bf16 through padded LDS, contiguous 64B/thread global stores.
// ---------------------------------------------------------------------------
__device__ __forceinline__ void gemm_body(
    const unsigned short* A0, const unsigned short* Wp0,
    const unsigned short* A1, const unsigned short* Wp1,
    const unsigned short* agg, const float* b0, const float* b1,
    unsigned short* out, int M, int rowBase, unsigned short* sO)
{
    const int t = threadIdx.x, wave = t >> 6, lane = t & 63;
    int arow = rowBase + wave * 16 + (lane & 15);
    if (arow >= M) arow = M - 1;
    const bf16x8* Ap0 = (const bf16x8*)(A0 + (size_t)arow * DIM + (lane >> 4) * 8);
    const bf16x8* Bp0 = (const bf16x8*)Wp0;
    f32x4 acc[8] = {};
    if (A1) {
        const bf16x8* Ap1 = (const bf16x8*)(A1 + (size_t)arow * DIM + (lane >> 4) * 8);
        const bf16x8* Bp1 = (const bf16x8*)Wp1;
#pragma unroll
        for (int ks = 0; ks < 4; ++ks) {
            const bf16x8 a0 = Ap0[ks * 4];
            const bf16x8 a1 = Ap1[ks * 4];
#pragma unroll
            for (int tn = 0; tn < 8; ++tn) {
                acc[tn] = __builtin_amdgcn_mfma_f32_16x16x32_bf16(a0, Bp0[(tn * 4 + ks) * 64 + lane], acc[tn], 0, 0, 0);
                acc[tn] = __builtin_amdgcn_mfma_f32_16x16x32_bf16(a1, Bp1[(tn * 4 + ks) * 64 + lane], acc[tn], 0, 0, 0);
            }
        }
    } else {
#pragma unroll
        for (int ks = 0; ks < 4; ++ks) {
            const bf16x8 a0 = Ap0[ks * 4];
#pragma unroll
            for (int tn = 0; tn < 8; ++tn)
                acc[tn] = __builtin_amdgcn_mfma_f32_16x16x32_bf16(a0, Bp0[(tn * 4 + ks) * 64 + lane], acc[tn], 0, 0, 0);
        }
    }
    const int col0 = lane & 15;
    const int lrow0 = wave * 16 + (lane >> 4) * 4;
#pragma unroll
    for (int tn = 0; tn < 8; ++tn) {
        const int col = tn * 16 + col0;
        float bv = 0.0f;
        if (b0) bv += b0[col];
        if (b1) bv += b1[col];
#pragma unroll
        for (int r = 0; r < 4; ++r) {
            float v = acc[tn][r] + bv;
            if (agg) v += bf2f(agg[(size_t)(rowBase + lrow0 + r) * DIM + col]);
            sO[(lrow0 + r) * 132 + col] = f2bf(v);
        }
    }
    __syncthreads();
    const int lr = t >> 2, lc = (t & 3) * 32;
    const int grow = rowBase + lr;
    if (grow < M) {
        unsigned short* po = out + (size_t)grow * DIM + lc;
        const unsigned short* ps = sO + lr * 132 + lc;
#pragma unroll
        for (int j = 0; j < 8; ++j)
            *(u16x4*)(po + j * 4) = *(const u16x4*)(ps + j * 4);
    }
}

__global__ __launch_bounds__(256) void gemm_fused(
    const unsigned short* __restrict__ A0, const unsigned short* __restrict__ Wp0,
    const unsigned short* __restrict__ A1, const unsigned short* __restrict__ Wp1,
    const unsigned short* __restrict__ agg,
    const float* __restrict__ b0, const float* __restrict__ b1,
    unsigned short* __restrict__ out, int M)
{
    __shared__ unsigned short sO[64 * 132];
    gemm_body(A0, Wp0, A1, Wp1, agg, b0, b1, out, M, blockIdx.x * 64, sO);
}

// subject + region updates in one dispatch: blocks [0,split) subject, rest region
__global__ __launch_bounds__(256) void gemm_pair(
    const unsigned short* As0, const unsigned short* Ws0,
    const unsigned short* As1, const unsigned short* Ws1,
    const float* bs0, unsigned short* outS, int Ms,
    const unsigned short* Ar0, const unsigned short* Wr0,
    const unsigned short* Ar1, const unsigned short* Wr1,
    const unsigned short* aggr, const float* br0, const float* br1,
    unsigned short* outR, int Mr, int split)
{
    __shared__ unsigned short sO[64 * 132];
    const int bid = blockIdx.x;
    if (bid < split)
        gemm_body(As0, Ws0, As1, Ws1, nullptr, bs0, nullptr, outS, Ms, bid * 64, sO);
    else
        gemm_body(Ar0, Wr0, Ar1, Wr1, aggr, br0, br1, outR, Mr, (bid - split) * 64, sO);
}

// ---------------------------------------------------------------------------
// Batched CSR build. count3 also records each edge's rank within its dst
// (the atomicAdd return value) so fill3 needs NO atomics.
// ---------------------------------------------------------------------------
__global__ void count3(const int* __restrict__ d0, const int* __restrict__ d1,
                       const int* __restrict__ d2, int* __restrict__ cntAll,
                       int* __restrict__ rank)
{
    const int b = blockIdx.x;
    const int type = b / EB;
    const int e = (b - type * EB) * 256 + threadIdx.x;
    if (e >= NEDGE) return;
    const int* dst = (type == 0) ? d0 : (type == 1) ? d1 : d2;
    const int base = (type == 0) ? 0 : (type == 1) ? PS : PS + PR;
    rank[(size_t)type * NEDGE + e] = atomicAdd(&cntAll[base + dst[e]], 1);
}

__global__ void scan3(const int* __restrict__ in, int* __restrict__ incl,
                      int* __restrict__ partial)
{
    __shared__ int s[256];
    const int t = threadIdx.x;
    const int i = blockIdx.x * 256 + t;     // CNT_ALL = 861*256 exactly
    s[t] = in[i];
    __syncthreads();
#pragma unroll
    for (int off = 1; off < 256; off <<= 1) {
        const int u = (t >= off) ? s[t - off] : 0;
        __syncthreads();
        s[t] += u;
        __syncthreads();
    }
    incl[i] = s[t];
    if (t == 255) partial[blockIdx.x] = s[255];
}

__global__ void scan_partials3(int* __restrict__ partial)
{
    const int b = blockIdx.x;
    const int start = (b == 0) ? 0 : (b == 1) ? NBS : NBS + NBR;
    const int len = (b == 0) ? NBS : NBR;
    __shared__ int s[512];
    const int t = threadIdx.x;
    s[t] = (t < len) ? partial[start + t] : 0;
    __syncthreads();
#pragma unroll
    for (int off = 1; off < 512; off <<= 1) {
        const int u = (t >= off) ? s[t - off] : 0;
        __syncthreads();
        s[t] += u;
        __syncthreads();
    }
    if (t < len) partial[start + t] = s[t];
}

__global__ void make_offsets3(const int* __restrict__ incl, const int* __restrict__ partial,
                              int* __restrict__ offRev, int* __restrict__ offHr,
                              int* __restrict__ offFc)
{
    const int b = blockIdx.x, t = threadIdx.x;
    int lb, n, segStart; int* off;
    if (b < NBS)            { lb = b;             n = NSUB; segStart = 0;         off = offRev; }
    else if (b < NBS + NBR) { lb = b - NBS;       n = NREG; segStart = NBS;       off = offHr; }
    else                    { lb = b - NBS - NBR; n = NREG; segStart = NBS + NBR; off = offFc; }
    const int i = lb * 256 + t;
    if (i >= n) return;
    const int add = (lb > 0) ? partial[segStart + lb - 1] : 0;
    off[i + 1] = incl[b * 256 + t] + add;
    if (i == 0) off[0] = 0;
}

// atomic-free fill: slot = off[dst] + rank (rank captured in count3)
__global__ void fill3(const int* __restrict__ s0, const int* __restrict__ d0,
                      const int* __restrict__ s1, const int* __restrict__ d1,
                      const int* __restrict__ s2, const int* __restrict__ d2,
                      const int* __restrict__ offRev, const int* __restrict__ offHr,
                      const int* __restrict__ offFc, const int* __restrict__ rank,
                      int* __restrict__ csrRev, int* __restrict__ csrHr,
                      int* __restrict__ csrFc)
{
    const int b = blockIdx.x;
    const int type = b / EB;
    const int e = (b - type * EB) * 256 + threadIdx.x;
    if (e >= NEDGE) return;
    const int* src = (type == 0) ? s0 : (type == 1) ? s1 : s2;
    const int* dst = (type == 0) ? d0 : (type == 1) ? d1 : d2;
    const int* off = (type == 0) ? offRev : (type == 1) ? offHr : offFc;
    int* csr = (type == 0) ? csrRev : (type == 1) ? csrHr : csrFc;
    const int d = dst[e];
    csr[off[d] + rank[(size_t)type * NEDGE + e]] = src[e];
}

__global__ void derive3(const int* __restrict__ offRev, const int* __restrict__ offHr,
                        const int* __restrict__ offFc, float* __restrict__ invS,
                        float* __restrict__ invR, float* __restrict__ dis)
{
    int i = blockIdx.x * 256 + threadIdx.x;
    if (i < NSUB) {
        const int c = offRev[i + 1] - offRev[i];
        invS[i] = 1.0f / fmaxf((float)c, 1.0f);
        return;
    }
    i -= NSUB;
    if (i < NREG) {
        const int c = offHr[i + 1] - offHr[i];
        invR[i] = 1.0f / fmaxf((float)c, 1.0f);
        return;
    }
    i -= NREG;
    if (i < NREG) {
        const int c = offFc[i + 1] - offFc[i];
        dis[i] = rsqrtf((float)(c + 1));      // +1 self loop
    }
}

// ---------------------------------------------------------------------------
// pack all 5 weight tensors [LAY][128][128] into MFMA B-fragment layout
// ---------------------------------------------------------------------------
__global__ void pack5(const float* __restrict__ w0, const float* __restrict__ w1,
                      const float* __restrict__ w2, const float* __restrict__ w3,
                      const float* __restrict__ w4,
                      unsigned short* __restrict__ p0, unsigned short* __restrict__ p1,
                      unsigned short* __restrict__ p2, unsigned short* __restrict__ p3,
                      unsigned short* __restrict__ p4)
{
    const int tid = blockIdx.x * 256 + threadIdx.x;   // 5*LAY*2048 = 20480
    const int which = tid >> 12;
    const int rem = tid & 4095;
    const float* W = (which == 0) ? w0 : (which == 1) ? w1 : (which == 2) ? w2 : (which == 3) ? w3 : w4;
    unsigned short* P = (which == 0) ? p0 : (which == 1) ? p1 : (which == 2) ? p2 : (which == 3) ? p3 : p4;
    const int m = rem >> 11;
    const int rr = rem & 2047;
    const int f = rr >> 6, l = rr & 63;
    const int n0 = (f >> 2) * 16, k0 = (f & 3) * 32;
    const float* Wm = W + (size_t)m * DIM * DIM;
    unsigned short* Pm = P + (size_t)m * 32 * 512 + ((size_t)f * 64 + l) * 8;
    const int kb = k0 + (l >> 4) * 8, n = n0 + (l & 15);
#pragma unroll
    for (int j = 0; j < 8; ++j) Pm[j] = f2bf(Wm[(kb + j) * DIM + n]);
}

__global__ void cvt2(const float* __restrict__ xs, const float* __restrict__ xr,
                     unsigned short* __restrict__ outS, unsigned short* __restrict__ outR)
{
    const int i = blockIdx.x * 256 + threadIdx.x;
    const int nS = NSUB * DIM / 4;
    const float* in;
    unsigned short* out;
    int base;
    if (i < nS) { in = xs; out = outS; base = i * 4; }
    else {
        const int j = i - nS;
        if (j >= NREG * DIM / 4) return;
        in = xr; out = outR; base = j * 4;
    }
    const float4 v = *(const float4*)(in + base);
    u16x4 o; o[0] = f2bf(v.x); o[1] = f2bf(v.y); o[2] = f2bf(v.z); o[3] = f2bf(v.w);
    *(u16x4*)(out + base) = o;
}

// ---------------------------------------------------------------------------
// Merged gathers: 16 lanes/row, u16x8 per lane.
// ---------------------------------------------------------------------------
__global__ __launch_bounds__(256) void gather_all(
    const unsigned short* __restrict__ txS, const unsigned short* __restrict__ xr,
    const int* __restrict__ offHr, const int* __restrict__ csrHr, const float* __restrict__ invR,
    const int* __restrict__ offFc, const int* __restrict__ csrFc, const float* __restrict__ dis,
    const int* __restrict__ offRev, const int* __restrict__ csrRev, const float* __restrict__ invS,
    unsigned short* __restrict__ aggR, unsigned short* __restrict__ h,
    unsigned short* __restrict__ aggS)
{
    const int tid = blockIdx.x * 256 + threadIdx.x;
    const int g = tid >> 4;
    const int c0 = (tid & 15) * 8;
    if (g < NREG) {
        float acc[8] = {0, 0, 0, 0, 0, 0, 0, 0};
        const int j1 = offHr[g + 1];
        for (int j = offHr[g]; j < j1; ++j) {
            const u16x8 v = *(const u16x8*)(txS + (size_t)csrHr[j] * DIM + c0);
#pragma unroll
            for (int i = 0; i < 8; ++i) acc[i] += bf2f(v[i]);
        }
        const float sR = invR[g];
        u16x8 o;
#pragma unroll
        for (int i = 0; i < 8; ++i) o[i] = f2bf(acc[i] * sR);
        *(u16x8*)(aggR + (size_t)g * DIM + c0) = o;

        float a2[8] = {0, 0, 0, 0, 0, 0, 0, 0};
        const int j3 = offFc[g + 1];
        for (int j = offFc[g]; j < j3; ++j) {
            const int s = csrFc[j];
            const float w = dis[s];
            const u16x8 v = *(const u16x8*)(xr + (size_t)s * DIM + c0);
#pragma unroll
            for (int i = 0; i < 8; ++i) a2[i] += w * bf2f(v[i]);
        }
        const float dd = dis[g];
        const u16x8 sf = *(const u16x8*)(xr + (size_t)g * DIM + c0);
        u16x8 oh;
#pragma unroll
        for (int i = 0; i < 8; ++i) oh[i] = f2bf(dd * a2[i] + dd * dd * bf2f(sf[i]));
        *(u16x8*)(h + (size_t)g * DIM + c0) = oh;
    } else {
        const int gs = g - NREG;
        if (gs >= NSUB) return;
        float acc[8] = {0, 0, 0, 0, 0, 0, 0, 0};
        const int j1 = offRev[gs + 1];
        for (int j = offRev[gs]; j < j1; ++j) {
            const u16x8 v = *(const u16x8*)(xr + (size_t)csrRev[j] * DIM + c0);
#pragma unroll
            for (int i = 0; i < 8; ++i) acc[i] += bf2f(v[i]);
        }
        const float sS = invS[gs];
        u16x8 o;
#pragma unroll
        for (int i = 0; i < 8; ++i) o[i] = f2bf(acc[i] * sS);
        *(u16x8*)(aggS + (size_t)gs * DIM + c0) = o;
    }
}

// merged output projections
__global__ void lin2(const unsigned short* __restrict__ XS, const unsigned short* __restrict__ XR,
                     const float* __restrict__ Ws, const float* __restrict__ bs,
                     const float* __restrict__ Wr, const float* __restrict__ br,
                     float* __restrict__ out)
{
    const int r = blockIdx.x * 256 + threadIdx.x;
    if (r >= NSUB + NREG) return;
    const unsigned short* X;
    const float *W, *b;
    size_t row;
    if (r < NSUB) { X = XS; W = Ws; b = bs; row = r; }
    else          { X = XR; W = Wr; b = br; row = r - NSUB; }
    float a0 = b[0], a1 = b[1];
    const unsigned short* xp = X + row * DIM;
#pragma unroll
    for (int k = 0; k < DIM; k += 8) {
        const u16x8 v = *(const u16x8*)(xp + k);
#pragma unroll
        for (int i = 0; i < 8; ++i) {
            const float x = bf2f(v[i]);
            a0 += x * W[(k + i) * 2 + 0];
            a1 += x * W[(k + i) * 2 + 1];
        }
    }
    out[(size_t)r * 2 + 0] = a0;
    out[(size_t)r * 2 + 1] = a1;
}

extern "C" void kernel_launch(void* const* d_in, const int* in_sizes, int n_in,
                              void* d_out, int out_size, void* d_ws, size_t ws_size,
                              hipStream_t stream)
{
    const float* x_subject = (const float*)d_in[0];
    const float* x_region  = (const float*)d_in[1];
    const int*   ei_hr     = (const int*)d_in[2];
    const int*   ei_rev    = (const int*)d_in[3];
    const int*   ei_fc     = (const int*)d_in[4];
    const float* sr_Wl = (const float*)d_in[5];
    const float* sr_Wr = (const float*)d_in[6];
    const float* sr_b  = (const float*)d_in[7];
    const float* rs_Wl = (const float*)d_in[8];
    const float* rs_Wr = (const float*)d_in[9];
    const float* rs_b  = (const float*)d_in[10];
    const float* gcn_W = (const float*)d_in[11];
    const float* gcn_b = (const float*)d_in[12];
    const float* lsW   = (const float*)d_in[13];
    const float* lsb   = (const float*)d_in[14];
    const float* lrW   = (const float*)d_in[15];
    const float* lrb   = (const float*)d_in[16];

    // ---- workspace layout: f32 | bf16 | int32
    float* fp = (float*)d_ws;
    float* invS = fp; fp += NSUB;
    float* invR = fp; fp += NREG;
    float* dis  = fp; fp += NREG;
    unsigned short* up = (unsigned short*)fp;
    unsigned short* xsA  = up; up += (size_t)NSUB * DIM;
    unsigned short* xsB  = up; up += (size_t)NSUB * DIM;
    unsigned short* txS  = up; up += (size_t)NSUB * DIM;
    unsigned short* aggS = up; up += (size_t)NSUB * DIM;
    unsigned short* xrA  = up; up += (size_t)NREG * DIM;
    unsigned short* xrB  = up; up += (size_t)NREG * DIM;
    unsigned short* aggR = up; up += (size_t)NREG * DIM;
    unsigned short* h    = up; up += (size_t)NREG * DIM;
    unsigned short* pSrWl = up; up += (size_t)LAY * 16384;
    unsigned short* pSrWr = up; up += (size_t)LAY * 16384;
    unsigned short* pRsWl = up; up += (size_t)LAY * 16384;
    unsigned short* pRsWr = up; up += (size_t)LAY * 16384;
    unsigned short* pGcn  = up; up += (size_t)LAY * 16384;
    int* ip = (int*)up;
    int* offRev = ip; ip += NSUB + 1;
    int* offHr  = ip; ip += NREG + 1;
    int* offFc  = ip; ip += NREG + 2;   // pad
    int* csrRev = ip; ip += NEDGE;
    int* csrHr  = ip; ip += NEDGE;
    int* csrFc  = ip; ip += NEDGE;
    int* rank   = ip; ip += 3 * NEDGE;
    int* cntAll = ip; ip += CNT_ALL;
    int* inclAll = ip; ip += CNT_ALL;
    int* partAll = ip; ip += 1024;

    // ---- CSR build (batched across the 3 edge types; fill has no atomics)
    hipMemsetAsync(cntAll, 0, CNT_ALL * sizeof(int), stream);
    count3<<<3 * EB, 256, 0, stream>>>(ei_rev + NEDGE, ei_hr + NEDGE, ei_fc + NEDGE,
                                       cntAll, rank);
    scan3<<<NBLK, 256, 0, stream>>>(cntAll, inclAll, partAll);
    scan_partials3<<<3, 512, 0, stream>>>(partAll);
    make_offsets3<<<NBLK, 256, 0, stream>>>(inclAll, partAll, offRev, offHr, offFc);
    fill3<<<3 * EB, 256, 0, stream>>>(ei_rev, ei_rev + NEDGE, ei_hr, ei_hr + NEDGE,
                                      ei_fc, ei_fc + NEDGE, offRev, offHr, offFc,
                                      rank, csrRev, csrHr, csrFc);
    derive3<<<(NSUB + 2 * NREG + 255) / 256, 256, 0, stream>>>(offRev, offHr, offFc, invS, invR, dis);

    // ---- weight packing + input conversion
    pack5<<<80, 256, 0, stream>>>(sr_Wl, sr_Wr, rs_Wl, rs_Wr, gcn_W,
                                  pSrWl, pSrWr, pRsWl, pRsWr, pGcn);
    cvt2<<<(NSUB + NREG) * DIM / 4 / 256, 256, 0, stream>>>(x_subject, x_region, xsA, xrA);

    const unsigned short* cxs = xsA;
    const unsigned short* cxr = xrA;
    unsigned short* nxs_l[2] = { xsB, xsA };
    unsigned short* nxr_l[2] = { xrB, xrA };
    const int SGB = (NSUB + 63) / 64;      // 313
    const int RGB = (NREG + 63) / 64;      // 1563
    const int GA = ((NREG + NSUB) * 16) / 256;   // 7500

    for (int l = 0; l < LAY; ++l) {
        unsigned short* nxs = nxs_l[l];
        unsigned short* nxr = nxr_l[l];
        const size_t pOff = (size_t)l * 16384;
        const size_t bOff = (size_t)l * DIM;

        // 1) txS = xs @ sr_Wl   (transform-first for hr edges)
        gemm_fused<<<SGB, 256, 0, stream>>>(cxs, pSrWl + pOff, nullptr, nullptr,
                                            nullptr, nullptr, nullptr, txS, NSUB);
        // 2) aggR = invR*gather_hr(txS); h = GCN-aggregate(xr); aggS = invS*gather_rev(xr)
        gather_all<<<GA, 256, 0, stream>>>(txS, cxr, offHr, csrHr, invR,
                                           offFc, csrFc, dis, offRev, csrRev, invS,
                                           aggR, h, aggS);
        // 3+4) subject and region updates in one dispatch
        gemm_pair<<<SGB + RGB, 256, 0, stream>>>(
            cxs, pRsWr + pOff, aggS, pRsWl + pOff, rs_b + bOff, nxs, NSUB,
            cxr, pSrWr + pOff, h, pGcn + pOff, aggR, sr_b + bOff, gcn_b + bOff,
            nxr, NREG, SGB);
        cxs = nxs;
        cxr = nxr;
    }

    // ---- output projections
    lin2<<<(NSUB + NREG + 255) / 256, 256, 0, stream>>>(cxs, cxr, lsW, lsb, lrW, lrb,
                                                        (float*)d_out);
}

// Round 6
// 422.273 us; speedup vs baseline: 16.1623x; 1.0304x over previous
//
#include <hip/hip_runtime.h>

#define NSUB 20000
#define NREG 100000
#define NEDGE 600000
#define DIM 128
#define LAY 2
#define NOUT 2

#define EB 2344              // edge blocks (256 thr): 2344*256 >= 600000
#define NBS 79               // node scan blocks, subject (79*256=20224)
#define NBR 391              // node scan blocks, region  (391*256=100096)
#define PS (NBS * 256)
#define PR (NBR * 256)
#define CNT_ALL (PS + 2 * PR)  // 861*256
#define NBLK (NBS + 2 * NBR)   // 861

typedef __attribute__((ext_vector_type(8))) short bf16x8;
typedef __attribute__((ext_vector_type(8))) unsigned short u16x8;
typedef __attribute__((ext_vector_type(4))) unsigned short u16x4;
typedef __attribute__((ext_vector_type(4))) float f32x4;

__device__ __forceinline__ float bf2f(unsigned short u) {
    return __uint_as_float(((unsigned)u) << 16);
}
__device__ __forceinline__ unsigned short f2bf(float f) {
    unsigned x = __float_as_uint(f);
    unsigned r = ((x >> 16) & 1u) + 0x7fffu;   // RNE
    return (unsigned short)((x + r) >> 16);
}

// ---------------------------------------------------------------------------
// MFMA GEMM body, 128-row tile: 4 waves, each wave owns rows
// [wave*32, wave*32+32) as two 16-row groups sharing every B fragment
// (halves W-fragment traffic vs 64-row tiles). Epilogue adds bias/agg,
// stages bf16 via padded LDS, contiguous stores.
// ---------------------------------------------------------------------------
__device__ __forceinline__ void gemm_body(
    const unsigned short* A0, const unsigned short* Wp0,
    const unsigned short* A1, const unsigned short* Wp1,
    const unsigned short* agg, const float* b0, const float* b1,
    unsigned short* out, int M, int rowBase, unsigned short* sO)
{
    const int t = threadIdx.x, wave = t >> 6, lane = t & 63;
    int ar0 = rowBase + wave * 32 + (lane & 15);
    int ar1 = ar0 + 16;
    if (ar0 >= M) ar0 = M - 1;
    if (ar1 >= M) ar1 = M - 1;
    const bf16x8* Ap0g0 = (const bf16x8*)(A0 + (size_t)ar0 * DIM + (lane >> 4) * 8);
    const bf16x8* Ap0g1 = (const bf16x8*)(A0 + (size_t)ar1 * DIM + (lane >> 4) * 8);
    const bf16x8* Bp0 = (const bf16x8*)Wp0;
    f32x4 acc[2][8] = {};
    if (A1) {
        const bf16x8* Ap1g0 = (const bf16x8*)(A1 + (size_t)ar0 * DIM + (lane >> 4) * 8);
        const bf16x8* Ap1g1 = (const bf16x8*)(A1 + (size_t)ar1 * DIM + (lane >> 4) * 8);
        const bf16x8* Bp1 = (const bf16x8*)Wp1;
#pragma unroll
        for (int ks = 0; ks < 4; ++ks) {
            const bf16x8 a00 = Ap0g0[ks * 4];
            const bf16x8 a01 = Ap0g1[ks * 4];
            const bf16x8 a10 = Ap1g0[ks * 4];
            const bf16x8 a11 = Ap1g1[ks * 4];
#pragma unroll
            for (int tn = 0; tn < 8; ++tn) {
                const bf16x8 bA = Bp0[(tn * 4 + ks) * 64 + lane];
                const bf16x8 bB = Bp1[(tn * 4 + ks) * 64 + lane];
                acc[0][tn] = __builtin_amdgcn_mfma_f32_16x16x32_bf16(a00, bA, acc[0][tn], 0, 0, 0);
                acc[1][tn] = __builtin_amdgcn_mfma_f32_16x16x32_bf16(a01, bA, acc[1][tn], 0, 0, 0);
                acc[0][tn] = __builtin_amdgcn_mfma_f32_16x16x32_bf16(a10, bB, acc[0][tn], 0, 0, 0);
                acc[1][tn] = __builtin_amdgcn_mfma_f32_16x16x32_bf16(a11, bB, acc[1][tn], 0, 0, 0);
            }
        }
    } else {
#pragma unroll
        for (int ks = 0; ks < 4; ++ks) {
            const bf16x8 a00 = Ap0g0[ks * 4];
            const bf16x8 a01 = Ap0g1[ks * 4];
#pragma unroll
            for (int tn = 0; tn < 8; ++tn) {
                const bf16x8 bA = Bp0[(tn * 4 + ks) * 64 + lane];
                acc[0][tn] = __builtin_amdgcn_mfma_f32_16x16x32_bf16(a00, bA, acc[0][tn], 0, 0, 0);
                acc[1][tn] = __builtin_amdgcn_mfma_f32_16x16x32_bf16(a01, bA, acc[1][tn], 0, 0, 0);
            }
        }
    }
    const int col0 = lane & 15;
#pragma unroll
    for (int g = 0; g < 2; ++g) {
        const int lrow0 = wave * 32 + g * 16 + (lane >> 4) * 4;
#pragma unroll
        for (int tn = 0; tn < 8; ++tn) {
            const int col = tn * 16 + col0;
            float bv = 0.0f;
            if (b0) bv += b0[col];
            if (b1) bv += b1[col];
#pragma unroll
            for (int r = 0; r < 4; ++r) {
                float v = acc[g][tn][r] + bv;
                if (agg) {
                    int rr = rowBase + lrow0 + r;
                    if (rr >= M) rr = M - 1;
                    v += bf2f(agg[(size_t)rr * DIM + col]);
                }
                sO[(lrow0 + r) * 132 + col] = f2bf(v);
            }
        }
    }
    __syncthreads();
    // store 128 rows in 2 phases of the proven 2-way-free pattern
#pragma unroll
    for (int p = 0; p < 2; ++p) {
        const int lr = p * 64 + (t >> 2), lc = (t & 3) * 32;
        const int grow = rowBase + lr;
        if (grow < M) {
            unsigned short* po = out + (size_t)grow * DIM + lc;
            const unsigned short* ps = sO + lr * 132 + lc;
#pragma unroll
            for (int j = 0; j < 8; ++j)
                *(u16x4*)(po + j * 4) = *(const u16x4*)(ps + j * 4);
        }
    }
}

__global__ __launch_bounds__(256) void gemm_fused(
    const unsigned short* __restrict__ A0, const unsigned short* __restrict__ Wp0,
    const unsigned short* __restrict__ A1, const unsigned short* __restrict__ Wp1,
    const unsigned short* __restrict__ agg,
    const float* __restrict__ b0, const float* __restrict__ b1,
    unsigned short* __restrict__ out, int M)
{
    __shared__ unsigned short sO[128 * 132];
    gemm_body(A0, Wp0, A1, Wp1, agg, b0, b1, out, M, blockIdx.x * 128, sO);
}

// subject + region updates in one dispatch: blocks [0,split) subject, rest region
__global__ __launch_bounds__(256) void gemm_pair(
    const unsigned short* As0, const unsigned short* Ws0,
    const unsigned short* As1, const unsigned short* Ws1,
    const float* bs0, unsigned short* outS, int Ms,
    const unsigned short* Ar0, const unsigned short* Wr0,
    const unsigned short* Ar1, const unsigned short* Wr1,
    const unsigned short* aggr, const float* br0, const float* br1,
    unsigned short* outR, int Mr, int split)
{
    __shared__ unsigned short sO[128 * 132];
    const int bid = blockIdx.x;
    if (bid < split)
        gemm_body(As0, Ws0, As1, Ws1, nullptr, bs0, nullptr, outS, Ms, bid * 128, sO);
    else
        gemm_body(Ar0, Wr0, Ar1, Wr1, aggr, br0, br1, outR, Mr, (bid - split) * 128, sO);
}

// ---------------------------------------------------------------------------
// Batched CSR build; count3 records per-edge rank so fill3 is atomic-free.
// ---------------------------------------------------------------------------
__global__ void count3(const int* __restrict__ d0, const int* __restrict__ d1,
                       const int* __restrict__ d2, int* __restrict__ cntAll,
                       int* __restrict__ rank)
{
    const int b = blockIdx.x;
    const int type = b / EB;
    const int e = (b - type * EB) * 256 + threadIdx.x;
    if (e >= NEDGE) return;
    const int* dst = (type == 0) ? d0 : (type == 1) ? d1 : d2;
    const int base = (type == 0) ? 0 : (type == 1) ? PS : PS + PR;
    rank[(size_t)type * NEDGE + e] = atomicAdd(&cntAll[base + dst[e]], 1);
}

__global__ void scan3(const int* __restrict__ in, int* __restrict__ incl,
                      int* __restrict__ partial)
{
    __shared__ int s[256];
    const int t = threadIdx.x;
    const int i = blockIdx.x * 256 + t;
    s[t] = in[i];
    __syncthreads();
#pragma unroll
    for (int off = 1; off < 256; off <<= 1) {
        const int u = (t >= off) ? s[t - off] : 0;
        __syncthreads();
        s[t] += u;
        __syncthreads();
    }
    incl[i] = s[t];
    if (t == 255) partial[blockIdx.x] = s[255];
}

__global__ void scan_partials3(int* __restrict__ partial)
{
    const int b = blockIdx.x;
    const int start = (b == 0) ? 0 : (b == 1) ? NBS : NBS + NBR;
    const int len = (b == 0) ? NBS : NBR;
    __shared__ int s[512];
    const int t = threadIdx.x;
    s[t] = (t < len) ? partial[start + t] : 0;
    __syncthreads();
#pragma unroll
    for (int off = 1; off < 512; off <<= 1) {
        const int u = (t >= off) ? s[t - off] : 0;
        __syncthreads();
        s[t] += u;
        __syncthreads();
    }
    if (t < len) partial[start + t] = s[t];
}

__global__ void make_offsets3(const int* __restrict__ incl, const int* __restrict__ partial,
                              int* __restrict__ offRev, int* __restrict__ offHr,
                              int* __restrict__ offFc)
{
    const int b = blockIdx.x, t = threadIdx.x;
    int lb, n, segStart; int* off;
    if (b < NBS)            { lb = b;             n = NSUB; segStart = 0;         off = offRev; }
    else if (b < NBS + NBR) { lb = b - NBS;       n = NREG; segStart = NBS;       off = offHr; }
    else                    { lb = b - NBS - NBR; n = NREG; segStart = NBS + NBR; off = offFc; }
    const int i = lb * 256 + t;
    if (i >= n) return;
    const int add = (lb > 0) ? partial[segStart + lb - 1] : 0;
    off[i + 1] = incl[b * 256 + t] + add;
    if (i == 0) off[0] = 0;
}

__global__ void fill3(const int* __restrict__ s0, const int* __restrict__ d0,
                      const int* __restrict__ s1, const int* __restrict__ d1,
                      const int* __restrict__ s2, const int* __restrict__ d2,
                      const int* __restrict__ offRev, const int* __restrict__ offHr,
                      const int* __restrict__ offFc, const int* __restrict__ rank,
                      int* __restrict__ csrRev, int* __restrict__ csrHr,
                      int* __restrict__ csrFc)
{
    const int b = blockIdx.x;
    const int type = b / EB;
    const int e = (b - type * EB) * 256 + threadIdx.x;
    if (e >= NEDGE) return;
    const int* src = (type == 0) ? s0 : (type == 1) ? s1 : s2;
    const int* dst = (type == 0) ? d0 : (type == 1) ? d1 : d2;
    const int* off = (type == 0) ? offRev : (type == 1) ? offHr : offFc;
    int* csr = (type == 0) ? csrRev : (type == 1) ? csrHr : csrFc;
    const int d = dst[e];
    csr[off[d] + rank[(size_t)type * NEDGE + e]] = src[e];
}

__global__ void derive3(const int* __restrict__ offRev, const int* __restrict__ offHr,
                        const int* __restrict__ offFc, float* __restrict__ invS,
                        float* __restrict__ invR, float* __restrict__ dis)
{
    int i = blockIdx.x * 256 + threadIdx.x;
    if (i < NSUB) {
        const int c = offRev[i + 1] - offRev[i];
        invS[i] = 1.0f / fmaxf((float)c, 1.0f);
        return;
    }
    i -= NSUB;
    if (i < NREG) {
        const int c = offHr[i + 1] - offHr[i];
        invR[i] = 1.0f / fmaxf((float)c, 1.0f);
        return;
    }
    i -= NREG;
    if (i < NREG) {
        const int c = offFc[i + 1] - offFc[i];
        dis[i] = rsqrtf((float)(c + 1));      // +1 self loop
    }
}

// ---------------------------------------------------------------------------
// pack all 5 weight tensors into MFMA B-fragment layout
// ---------------------------------------------------------------------------
__global__ void pack5(const float* __restrict__ w0, const float* __restrict__ w1,
                      const float* __restrict__ w2, const float* __restrict__ w3,
                      const float* __restrict__ w4,
                      unsigned short* __restrict__ p0, unsigned short* __restrict__ p1,
                      unsigned short* __restrict__ p2, unsigned short* __restrict__ p3,
                      unsigned short* __restrict__ p4)
{
    const int tid = blockIdx.x * 256 + threadIdx.x;
    const int which = tid >> 12;
    const int rem = tid & 4095;
    const float* W = (which == 0) ? w0 : (which == 1) ? w1 : (which == 2) ? w2 : (which == 3) ? w3 : w4;
    unsigned short* P = (which == 0) ? p0 : (which == 1) ? p1 : (which == 2) ? p2 : (which == 3) ? p3 : p4;
    const int m = rem >> 11;
    const int rr = rem & 2047;
    const int f = rr >> 6, l = rr & 63;
    const int n0 = (f >> 2) * 16, k0 = (f & 3) * 32;
    const float* Wm = W + (size_t)m * DIM * DIM;
    unsigned short* Pm = P + (size_t)m * 32 * 512 + ((size_t)f * 64 + l) * 8;
    const int kb = k0 + (l >> 4) * 8, n = n0 + (l & 15);
#pragma unroll
    for (int j = 0; j < 8; ++j) Pm[j] = f2bf(Wm[(kb + j) * DIM + n]);
}

__global__ void cvt2(const float* __restrict__ xs, const float* __restrict__ xr,
                     unsigned short* __restrict__ outS, unsigned short* __restrict__ outR)
{
    const int i = blockIdx.x * 256 + threadIdx.x;
    const int nS = NSUB * DIM / 4;
    const float* in;
    unsigned short* out;
    int base;
    if (i < nS) { in = xs; out = outS; base = i * 4; }
    else {
        const int j = i - nS;
        if (j >= NREG * DIM / 4) return;
        in = xr; out = outR; base = j * 4;
    }
    const float4 v = *(const float4*)(in + base);
    u16x4 o; o[0] = f2bf(v.x); o[1] = f2bf(v.y); o[2] = f2bf(v.z); o[3] = f2bf(v.w);
    *(u16x4*)(out + base) = o;
}

// ---------------------------------------------------------------------------
// Gathers: 16 lanes/row, u16x8/lane, 4-deep software pipeline for MLP.
// ---------------------------------------------------------------------------
__device__ __forceinline__ void gather_rows(
    const unsigned short* feat, const int* csr, int j, int j1, int c0,
    const float* wts, float acc[8])
{
    for (; j + 4 <= j1; j += 4) {
        const int s0 = csr[j + 0], s1 = csr[j + 1], s2 = csr[j + 2], s3 = csr[j + 3];
        const u16x8 v0 = *(const u16x8*)(feat + (size_t)s0 * DIM + c0);
        const u16x8 v1 = *(const u16x8*)(feat + (size_t)s1 * DIM + c0);
        const u16x8 v2 = *(const u16x8*)(feat + (size_t)s2 * DIM + c0);
        const u16x8 v3 = *(const u16x8*)(feat + (size_t)s3 * DIM + c0);
        const float w0 = wts ? wts[s0] : 1.0f;
        const float w1 = wts ? wts[s1] : 1.0f;
        const float w2 = wts ? wts[s2] : 1.0f;
        const float w3 = wts ? wts[s3] : 1.0f;
#pragma unroll
        for (int i = 0; i < 8; ++i)
            acc[i] += w0 * bf2f(v0[i]) + w1 * bf2f(v1[i]) +
                      w2 * bf2f(v2[i]) + w3 * bf2f(v3[i]);
    }
    for (; j < j1; ++j) {
        const int s = csr[j];
        const u16x8 v = *(const u16x8*)(feat + (size_t)s * DIM + c0);
        const float w = wts ? wts[s] : 1.0f;
#pragma unroll
        for (int i = 0; i < 8; ++i) acc[i] += w * bf2f(v[i]);
    }
}

__global__ __launch_bounds__(256) void gather_all(
    const unsigned short* __restrict__ txS, const unsigned short* __restrict__ xr,
    const int* __restrict__ offHr, const int* __restrict__ csrHr, const float* __restrict__ invR,
    const int* __restrict__ offFc, const int* __restrict__ csrFc, const float* __restrict__ dis,
    const int* __restrict__ offRev, const int* __restrict__ csrRev, const float* __restrict__ invS,
    unsigned short* __restrict__ aggR, unsigned short* __restrict__ h,
    unsigned short* __restrict__ aggS)
{
    const int tid = blockIdx.x * 256 + threadIdx.x;
    const int g = tid >> 4;
    const int c0 = (tid & 15) * 8;
    if (g < NREG) {
        float acc[8] = {0, 0, 0, 0, 0, 0, 0, 0};
        gather_rows(txS, csrHr, offHr[g], offHr[g + 1], c0, nullptr, acc);
        const float sR = invR[g];
        u16x8 o;
#pragma unroll
        for (int i = 0; i < 8; ++i) o[i] = f2bf(acc[i] * sR);
        *(u16x8*)(aggR + (size_t)g * DIM + c0) = o;

        float a2[8] = {0, 0, 0, 0, 0, 0, 0, 0};
        gather_rows(xr, csrFc, offFc[g], offFc[g + 1], c0, dis, a2);
        const float dd = dis[g];
        const u16x8 sf = *(const u16x8*)(xr + (size_t)g * DIM + c0);
        u16x8 oh;
#pragma unroll
        for (int i = 0; i < 8; ++i) oh[i] = f2bf(dd * a2[i] + dd * dd * bf2f(sf[i]));
        *(u16x8*)(h + (size_t)g * DIM + c0) = oh;
    } else {
        const int gs = g - NREG;
        if (gs >= NSUB) return;
        float acc[8] = {0, 0, 0, 0, 0, 0, 0, 0};
        gather_rows(xr, csrRev, offRev[gs], offRev[gs + 1], c0, nullptr, acc);
        const float sS = invS[gs];
        u16x8 o;
#pragma unroll
        for (int i = 0; i < 8; ++i) o[i] = f2bf(acc[i] * sS);
        *(u16x8*)(aggS + (size_t)gs * DIM + c0) = o;
    }
}

// merged output projections
__global__ void lin2(const unsigned short* __restrict__ XS, const unsigned short* __restrict__ XR,
                     const float* __restrict__ Ws, const float* __restrict__ bs,
                     const float* __restrict__ Wr, const float* __restrict__ br,
                     float* __restrict__ out)
{
    const int r = blockIdx.x * 256 + threadIdx.x;
    if (r >= NSUB + NREG) return;
    const unsigned short* X;
    const float *W, *b;
    size_t row;
    if (r < NSUB) { X = XS; W = Ws; b = bs; row = r; }
    else          { X = XR; W = Wr; b = br; row = r - NSUB; }
    float a0 = b[0], a1 = b[1];
    const unsigned short* xp = X + row * DIM;
#pragma unroll
    for (int k = 0; k < DIM; k += 8) {
        const u16x8 v = *(const u16x8*)(xp + k);
#pragma unroll
        for (int i = 0; i < 8; ++i) {
            const float x = bf2f(v[i]);
            a0 += x * W[(k + i) * 2 + 0];
            a1 += x * W[(k + i) * 2 + 1];
        }
    }
    out[(size_t)r * 2 + 0] = a0;
    out[(size_t)r * 2 + 1] = a1;
}

extern "C" void kernel_launch(void* const* d_in, const int* in_sizes, int n_in,
                              void* d_out, int out_size, void* d_ws, size_t ws_size,
                              hipStream_t stream)
{
    const float* x_subject = (const float*)d_in[0];
    const float* x_region  = (const float*)d_in[1];
    const int*   ei_hr     = (const int*)d_in[2];
    const int*   ei_rev    = (const int*)d_in[3];
    const int*   ei_fc     = (const int*)d_in[4];
    const float* sr_Wl = (const float*)d_in[5];
    const float* sr_Wr = (const float*)d_in[6];
    const float* sr_b  = (const float*)d_in[7];
    const float* rs_Wl = (const float*)d_in[8];
    const float* rs_Wr = (const float*)d_in[9];
    const float* rs_b  = (const float*)d_in[10];
    const float* gcn_W = (const float*)d_in[11];
    const float* gcn_b = (const float*)d_in[12];
    const float* lsW   = (const float*)d_in[13];
    const float* lsb   = (const float*)d_in[14];
    const float* lrW   = (const float*)d_in[15];
    const float* lrb   = (const float*)d_in[16];

    // ---- workspace layout: f32 | bf16 | int32
    float* fp = (float*)d_ws;
    float* invS = fp; fp += NSUB;
    float* invR = fp; fp += NREG;
    float* dis  = fp; fp += NREG;
    unsigned short* up = (unsigned short*)fp;
    unsigned short* xsA  = up; up += (size_t)NSUB * DIM;
    unsigned short* xsB  = up; up += (size_t)NSUB * DIM;
    unsigned short* txS  = up; up += (size_t)NSUB * DIM;
    unsigned short* aggS = up; up += (size_t)NSUB * DIM;
    unsigned short* xrA  = up; up += (size_t)NREG * DIM;
    unsigned short* xrB  = up; up += (size_t)NREG * DIM;
    unsigned short* aggR = up; up += (size_t)NREG * DIM;
    unsigned short* h    = up; up += (size_t)NREG * DIM;
    unsigned short* pSrWl = up; up += (size_t)LAY * 16384;
    unsigned short* pSrWr = up; up += (size_t)LAY * 16384;
    unsigned short* pRsWl = up; up += (size_t)LAY * 16384;
    unsigned short* pRsWr = up; up += (size_t)LAY * 16384;
    unsigned short* pGcn  = up; up += (size_t)LAY * 16384;
    int* ip = (int*)up;
    int* offRev = ip; ip += NSUB + 1;
    int* offHr  = ip; ip += NREG + 1;
    int* offFc  = ip; ip += NREG + 2;   // pad
    int* csrRev = ip; ip += NEDGE;
    int* csrHr  = ip; ip += NEDGE;
    int* csrFc  = ip; ip += NEDGE;
    int* rank   = ip; ip += 3 * NEDGE;
    int* cntAll = ip; ip += CNT_ALL;
    int* inclAll = ip; ip += CNT_ALL;
    int* partAll = ip; ip += 1024;

    // ---- CSR build (batched; fill has no atomics)
    hipMemsetAsync(cntAll, 0, CNT_ALL * sizeof(int), stream);
    count3<<<3 * EB, 256, 0, stream>>>(ei_rev + NEDGE, ei_hr + NEDGE, ei_fc + NEDGE,
                                       cntAll, rank);
    scan3<<<NBLK, 256, 0, stream>>>(cntAll, inclAll, partAll);
    scan_partials3<<<3, 512, 0, stream>>>(partAll);
    make_offsets3<<<NBLK, 256, 0, stream>>>(inclAll, partAll, offRev, offHr, offFc);
    fill3<<<3 * EB, 256, 0, stream>>>(ei_rev, ei_rev + NEDGE, ei_hr, ei_hr + NEDGE,
                                      ei_fc, ei_fc + NEDGE, offRev, offHr, offFc,
                                      rank, csrRev, csrHr, csrFc);
    derive3<<<(NSUB + 2 * NREG + 255) / 256, 256, 0, stream>>>(offRev, offHr, offFc, invS, invR, dis);

    // ---- weight packing + input conversion
    pack5<<<80, 256, 0, stream>>>(sr_Wl, sr_Wr, rs_Wl, rs_Wr, gcn_W,
                                  pSrWl, pSrWr, pRsWl, pRsWr, pGcn);
    cvt2<<<(NSUB + NREG) * DIM / 4 / 256, 256, 0, stream>>>(x_subject, x_region, xsA, xrA);

    const unsigned short* cxs = xsA;
    const unsigned short* cxr = xrA;
    unsigned short* nxs_l[2] = { xsB, xsA };
    unsigned short* nxr_l[2] = { xrB, xrA };
    const int SGB = (NSUB + 127) / 128;    // 157
    const int RGB = (NREG + 127) / 128;    // 782
    const int GA = ((NREG + NSUB) * 16) / 256;   // 7500

    for (int l = 0; l < LAY; ++l) {
        unsigned short* nxs = nxs_l[l];
        unsigned short* nxr = nxr_l[l];
        const size_t pOff = (size_t)l * 16384;
        const size_t bOff = (size_t)l * DIM;

        // 1) txS = xs @ sr_Wl   (transform-first for hr edges)
        gemm_fused<<<SGB, 256, 0, stream>>>(cxs, pSrWl + pOff, nullptr, nullptr,
                                            nullptr, nullptr, nullptr, txS, NSUB);
        // 2) aggR = invR*gather_hr(txS); h = GCN-aggregate(xr); aggS = invS*gather_rev(xr)
        gather_all<<<GA, 256, 0, stream>>>(txS, cxr, offHr, csrHr, invR,
                                           offFc, csrFc, dis, offRev, csrRev, invS,
                                           aggR, h, aggS);
        // 3+4) subject and region updates in one dispatch
        gemm_pair<<<SGB + RGB, 256, 0, stream>>>(
            cxs, pRsWr + pOff, aggS, pRsWl + pOff, rs_b + bOff, nxs, NSUB,
            cxr, pSrWr + pOff, h, pGcn + pOff, aggR, sr_b + bOff, gcn_b + bOff,
            nxr, NREG, SGB);
        cxs = nxs;
        cxr = nxr;
    }

    // ---- output projections
    lin2<<<(NSUB + NREG + 255) / 256, 256, 0, stream>>>(cxs, cxr, lsW, lsb, lrW, lrb,
                                                        (float*)d_out);
}